// Round 1
// baseline (99.278 us; speedup 1.0000x reference)
//
#include <hip/hip_runtime.h>

// Problem: B=4, S=4096, D_MODEL=200, head=50 (padded to 64), out fp32.
// Pipeline: prep_weights -> proj (MFMA) -> flash attn (MFMA, KV-split 4) ->
//           combine -> out-proj (MFMA, WO pre-summed over the 4 tiled heads).

typedef short s4 __attribute__((ext_vector_type(4)));
typedef float f4 __attribute__((ext_vector_type(4)));

#define SLEN 4096
#define NB 4
#define DMODEL 200
#define HREAL 50
#define HP 64
#define DMP 208
#define SPLIT 4
#define KVB 64
// (1/sqrt(50)) * log2(e) folded into WQ so softmax uses exp2 (v_exp_f32)
#define QSCALE 0.20402789f

__device__ __forceinline__ short f2bf(float f) {
  unsigned u = __builtin_bit_cast(unsigned, f);
  u += 0x7FFFu + ((u >> 16) & 1u);
  return (short)(u >> 16);
}

// ---------------- weight prep: transpose+pad+bf16 (and sum WO head blocks) ---
__global__ void prep_weights(const float* __restrict__ WQ, const float* __restrict__ WK,
                             const float* __restrict__ WV, const float* __restrict__ WO,
                             short* __restrict__ wqt, short* __restrict__ wkt,
                             short* __restrict__ wvt, short* __restrict__ wot) {
  int id = blockIdx.x * 256 + threadIdx.x;
  const int NW = HP * DMP;  // 13312
  if (id < 3 * NW) {
    int which = id / NW, rem = id % NW;
    int e = rem / DMP, d = rem % DMP;
    float v = 0.f;
    if (e < HREAL && d < DMODEL) {
      const float* W = (which == 0) ? WQ : (which == 1 ? WK : WV);
      v = W[d * HREAL + e];
      if (which == 0) v *= QSCALE;
    }
    short* T = (which == 0) ? wqt : (which == 1 ? wkt : wvt);
    T[e * DMP + d] = f2bf(v);
  } else if (id < 4 * NW) {
    int rem = id - 3 * NW;
    int dm = rem / HP, e = rem % HP;
    float v = 0.f;
    if (dm < DMODEL && e < HREAL) {
      v = WO[(e)*DMODEL + dm] + WO[(HREAL + e) * DMODEL + dm] +
          WO[(2 * HREAL + e) * DMODEL + dm] + WO[(3 * HREAL + e) * DMODEL + dm];
    }
    wot[dm * HP + e] = f2bf(v);
  }
}

// ---------------- projections: X[16384,200] @ WT^T -> bf16 [16384,64] --------
// mode 0: q->Qp (scaled), 1: k->Kp, 2: v->VpT (transposed store [B][64][S])
__global__ __launch_bounds__(256) void proj_kernel(
    const float* __restrict__ q, const float* __restrict__ k, const float* __restrict__ v,
    const short* __restrict__ wqt, const short* __restrict__ wkt, const short* __restrict__ wvt,
    short* __restrict__ Qp, short* __restrict__ Kp, short* __restrict__ VpT) {
  const int mode = blockIdx.z;
  const float* X = (mode == 0) ? q : (mode == 1 ? k : v);
  const short* WT = (mode == 0) ? wqt : (mode == 1 ? wkt : wvt);
  const int lane = threadIdx.x & 63, wid = threadIdx.x >> 6;
  const int l15 = lane & 15, g = lane >> 4;
  const int sbase = blockIdx.x * 64 + wid * 16;
  const int row = sbase + l15;
  f4 acc[4] = {};
  for (int c = 0; c < 13; ++c) {
    int d0 = 16 * c + 4 * g;
    f4 a4 = {};
    if (d0 < DMODEL) a4 = *(const f4*)(X + (size_t)row * DMODEL + d0);
    s4 af;
#pragma unroll
    for (int j = 0; j < 4; ++j) af[j] = f2bf(a4[j]);
#pragma unroll
    for (int n = 0; n < 4; ++n) {
      s4 bf = *(const s4*)(WT + (16 * n + l15) * DMP + d0);
      acc[n] = __builtin_amdgcn_mfma_f32_16x16x16bf16_1k(af, bf, acc[n], 0, 0, 0);
    }
  }
  if (mode < 2) {
    short* OUT = (mode == 0) ? Qp : Kp;
#pragma unroll
    for (int n = 0; n < 4; ++n)
#pragma unroll
      for (int r = 0; r < 4; ++r) {
        int rr = sbase + 4 * g + r;
        OUT[rr * HP + 16 * n + l15] = f2bf(acc[n][r]);
      }
  } else {
#pragma unroll
    for (int n = 0; n < 4; ++n)
#pragma unroll
      for (int r = 0; r < 4; ++r) {
        int rr = sbase + 4 * g + r;
        int bb = rr >> 12, s = rr & 4095;
        VpT[((bb * HP) + 16 * n + l15) * SLEN + s] = f2bf(acc[n][r]);
      }
  }
}

// ---------------- flash attention, swapped-operand QK^T, KV-split ------------
__global__ __launch_bounds__(256) void attn_kernel(
    const short* __restrict__ Qp, const short* __restrict__ Kp,
    const short* __restrict__ VpT, float* __restrict__ Mp,
    float* __restrict__ Lp, float* __restrict__ Op) {
  __shared__ short Klds[KVB * HP];  // [key][d], XOR-swizzled rows
  __shared__ short Vlds[HP * KVB];  // [d][key], XOR-swizzled rows
  const int tid = threadIdx.x;
  const int lane = tid & 63, wid = tid >> 6;
  const int l15 = lane & 15, g = lane >> 4;
  const int b = blockIdx.y, z = blockIdx.z;
  const int qrow = blockIdx.x * 64 + wid * 16 + l15;

  s4 qf[4];
  const short* qptr = Qp + (b * SLEN + qrow) * HP + 4 * g;
#pragma unroll
  for (int c = 0; c < 4; ++c) qf[c] = *(const s4*)(qptr + 16 * c);

  f4 o[4] = {};
  float m = -__builtin_inff();
  float lsum = 0.f;

  const int kv0 = z * (SLEN / SPLIT);
  for (int step = 0; step < (SLEN / SPLIT) / KVB; ++step) {
    const int kvbase = kv0 + step * KVB;
    __syncthreads();
    {
      const f4* srcK = (const f4*)(Kp + (size_t)(b * SLEN + kvbase) * HP);
#pragma unroll
      for (int i = 0; i < 2; ++i) {
        int ci = tid + i * 256;
        f4 val = srcK[ci];
        int ob = ci * 16; ob ^= ((ob >> 7) & 7) << 4;
        *(f4*)((char*)Klds + ob) = val;
      }
#pragma unroll
      for (int i = 0; i < 2; ++i) {
        int ci = tid + i * 256;
        int d = ci >> 3, ch = ci & 7;
        f4 val = *(const f4*)(VpT + (size_t)(b * HP + d) * SLEN + kvbase + ch * 8);
        int ob = ci * 16; ob ^= (d & 7) << 4;
        *(f4*)((char*)Vlds + ob) = val;
      }
    }
    __syncthreads();
#pragma unroll
    for (int tt = 0; tt < KVB / 16; ++tt) {
      // S^T tile [16 keys x 16 q] = K_tile . Q^T  (C: col=q=l15, row=key=4g+r)
      f4 st = {};
      int krow = tt * 16 + l15;
      const char* kbase = (const char*)Klds + krow * 128;
      int ksw = (krow & 7) << 4;
#pragma unroll
      for (int c = 0; c < 4; ++c) {
        s4 kf = *(const s4*)(kbase + ((32 * c + 8 * g) ^ ksw));
        st = __builtin_amdgcn_mfma_f32_16x16x16bf16_1k(kf, qf[c], st, 0, 0, 0);
      }
      float tmax = fmaxf(fmaxf(st[0], st[1]), fmaxf(st[2], st[3]));
      tmax = fmaxf(tmax, __shfl_xor(tmax, 16));
      tmax = fmaxf(tmax, __shfl_xor(tmax, 32));
      if (tmax > m) {
        float corr = exp2f(m - tmax);
        lsum *= corr;
#pragma unroll
        for (int n = 0; n < 4; ++n)
#pragma unroll
          for (int r = 0; r < 4; ++r) o[n][r] *= corr;
        m = tmax;
      }
      s4 pf;
      float ps = 0.f;
#pragma unroll
      for (int r = 0; r < 4; ++r) {
        float p = exp2f(st[r] - m);
        ps += p;
        pf[r] = f2bf(p);
      }
      lsum += ps;
      // O^T[d][q] += V^T . P  (P already in B-frag layout: col=q=l15, k=4g+r)
#pragma unroll
      for (int n = 0; n < 4; ++n) {
        int d = 16 * n + l15;
        s4 vf = *(const s4*)((const char*)Vlds + d * 128 + ((32 * tt + 8 * g) ^ ((d & 7) << 4)));
        o[n] = __builtin_amdgcn_mfma_f32_16x16x16bf16_1k(vf, pf, o[n], 0, 0, 0);
      }
    }
  }
  lsum += __shfl_xor(lsum, 16);
  lsum += __shfl_xor(lsum, 32);
  const int rowg = b * SLEN + qrow;
  if (lane < 16) {
    Mp[z * (NB * SLEN) + rowg] = m;
    Lp[z * (NB * SLEN) + rowg] = lsum;
  }
  float* op = Op + ((size_t)z * (NB * SLEN) + rowg) * HP;
#pragma unroll
  for (int n = 0; n < 4; ++n)
    *(f4*)(op + 16 * n + 4 * g) = o[n];
}

// ---------------- merge the 4 KV-split partials, normalize, -> bf16 ----------
__global__ __launch_bounds__(256) void combine_kernel(
    const float* __restrict__ Mp, const float* __restrict__ Lp,
    const float* __restrict__ Op, short* __restrict__ Ob) {
  int id = blockIdx.x * 256 + threadIdx.x;  // 262144 total
  int rowg = id >> 4;
  int dc = id & 15;
  const int NR = NB * SLEN;
  float m0 = Mp[rowg], m1 = Mp[NR + rowg], m2 = Mp[2 * NR + rowg], m3 = Mp[3 * NR + rowg];
  float mm = fmaxf(fmaxf(m0, m1), fmaxf(m2, m3));
  float w0 = exp2f(m0 - mm), w1 = exp2f(m1 - mm), w2 = exp2f(m2 - mm), w3 = exp2f(m3 - mm);
  float L = w0 * Lp[rowg] + w1 * Lp[NR + rowg] + w2 * Lp[2 * NR + rowg] + w3 * Lp[3 * NR + rowg];
  float inv = 1.0f / L;
  f4 v0 = *(const f4*)(Op + ((size_t)0 * NR + rowg) * HP + dc * 4);
  f4 v1 = *(const f4*)(Op + ((size_t)1 * NR + rowg) * HP + dc * 4);
  f4 v2 = *(const f4*)(Op + ((size_t)2 * NR + rowg) * HP + dc * 4);
  f4 v3 = *(const f4*)(Op + ((size_t)3 * NR + rowg) * HP + dc * 4);
  s4 ov;
#pragma unroll
  for (int i = 0; i < 4; ++i)
    ov[i] = f2bf((w0 * v0[i] + w1 * v1[i] + w2 * v2[i] + w3 * v3[i]) * inv);
  *(s4*)(Ob + (size_t)rowg * HP + dc * 4) = ov;
}

// ---------------- out-projection: O[16384,64(bf16)] @ WOsum -> out fp32 ------
__global__ __launch_bounds__(256) void outproj_kernel(
    const short* __restrict__ Ob, const short* __restrict__ wot,
    float* __restrict__ out) {
  const int lane = threadIdx.x & 63, wid = threadIdx.x >> 6;
  const int l15 = lane & 15, g = lane >> 4;
  const int sbase = blockIdx.x * 64 + wid * 16;
  s4 af[4];
  const short* arow = Ob + (size_t)(sbase + l15) * HP + 4 * g;
#pragma unroll
  for (int c = 0; c < 4; ++c) af[c] = *(const s4*)(arow + 16 * c);
  for (int n = 0; n < 13; ++n) {
    f4 acc = {};
    const short* brow = wot + (16 * n + l15) * HP + 4 * g;
#pragma unroll
    for (int c = 0; c < 4; ++c) {
      s4 bf = *(const s4*)(brow + 16 * c);
      acc = __builtin_amdgcn_mfma_f32_16x16x16bf16_1k(af[c], bf, acc, 0, 0, 0);
    }
    int dm = 16 * n + l15;
    if (dm < DMODEL) {
#pragma unroll
      for (int r = 0; r < 4; ++r) {
        int rr = sbase + 4 * g + r;
        out[(size_t)rr * DMODEL + dm] = acc[r];
      }
    }
  }
}

extern "C" void kernel_launch(void* const* d_in, const int* in_sizes, int n_in,
                              void* d_out, int out_size, void* d_ws, size_t ws_size,
                              hipStream_t stream) {
  const float* q = (const float*)d_in[0];
  const float* k = (const float*)d_in[1];
  const float* v = (const float*)d_in[2];
  const float* WQ = (const float*)d_in[3];
  const float* WK = (const float*)d_in[4];
  const float* WV = (const float*)d_in[5];
  const float* WO = (const float*)d_in[6];
  float* out = (float*)d_out;
  char* ws = (char*)d_ws;

  const size_t MB2 = 2097152;  // 16384*64*2 bytes
  short* wqt = (short*)(ws + 0);
  short* wkt = (short*)(ws + 32768);
  short* wvt = (short*)(ws + 65536);
  short* wot = (short*)(ws + 98304);
  short* Qp = (short*)(ws + 131072);
  short* Kp = (short*)(ws + 131072 + MB2);
  short* VpT = (short*)(ws + 131072 + 2 * MB2);
  short* Ob = (short*)(ws + 131072 + 3 * MB2);
  float* Mp = (float*)(ws + 131072 + 4 * MB2);
  float* Lp = (float*)(ws + 131072 + 4 * MB2 + 262144);
  float* Op = (float*)(ws + 131072 + 4 * MB2 + 2 * 262144);
  // total: 131072 + 8MB + 512KB + 16MB ~= 25MB

  prep_weights<<<dim3(208), dim3(256), 0, stream>>>(WQ, WK, WV, WO, wqt, wkt, wvt, wot);
  proj_kernel<<<dim3(256, 1, 3), dim3(256), 0, stream>>>(q, k, v, wqt, wkt, wvt, Qp, Kp, VpT);
  attn_kernel<<<dim3(64, NB, SPLIT), dim3(256), 0, stream>>>(Qp, Kp, VpT, Mp, Lp, Op);
  combine_kernel<<<dim3(1024), dim3(256), 0, stream>>>(Mp, Lp, Op, Ob);
  outproj_kernel<<<dim3(256), dim3(256), 0, stream>>>(Ob, wot, out);
}

// Round 4
// 81.230 us; speedup vs baseline: 1.2222x; 1.2222x over previous
//
#include <hip/hip_runtime.h>
#include <hip/hip_bf16.h>

// Problem: B=4, S=4096, D_MODEL=200, head=50 (padded to 64), out fp32.
// Pipeline: prep_weights -> proj (MFMA) -> flash attn (MFMA, KV-split) ->
//           combine -> out-proj (MFMA, WO pre-summed over the 4 tiled heads).

typedef short s4 __attribute__((ext_vector_type(4)));
typedef float f4 __attribute__((ext_vector_type(4)));

#define SLEN 4096
#define NB 4
#define DMODEL 200
#define HREAL 50
#define HP 64
#define DMP 208
#define KVB 64
// (1/sqrt(50)) * log2(e) folded into WQ so softmax uses exp2 (v_exp_f32)
#define QSCALE 0.20402789f

__device__ __forceinline__ short f2bf(float f) {
  unsigned u = __builtin_bit_cast(unsigned, f);
  u += 0x7FFFu + ((u >> 16) & 1u);
  return (short)(u >> 16);
}

__device__ __forceinline__ float fexp2(float x) { return __builtin_amdgcn_exp2f(x); }

// ---------------- weight prep: transpose+pad+bf16 (and sum WO head blocks) ---
__global__ void prep_weights(const float* __restrict__ WQ, const float* __restrict__ WK,
                             const float* __restrict__ WV, const float* __restrict__ WO,
                             short* __restrict__ wqt, short* __restrict__ wkt,
                             short* __restrict__ wvt, short* __restrict__ wot) {
  int id = blockIdx.x * 256 + threadIdx.x;
  const int NW = HP * DMP;  // 13312
  if (id < 3 * NW) {
    int which = id / NW, rem = id % NW;
    int e = rem / DMP, d = rem % DMP;
    float v = 0.f;
    if (e < HREAL && d < DMODEL) {
      const float* W = (which == 0) ? WQ : (which == 1 ? WK : WV);
      v = W[d * HREAL + e];
      if (which == 0) v *= QSCALE;
    }
    short* T = (which == 0) ? wqt : (which == 1 ? wkt : wvt);
    T[e * DMP + d] = f2bf(v);
  } else if (id < 4 * NW) {
    int rem = id - 3 * NW;
    int dm = rem / HP, e = rem % HP;
    float v = 0.f;
    if (dm < DMODEL && e < HREAL) {
      v = WO[(e)*DMODEL + dm] + WO[(HREAL + e) * DMODEL + dm] +
          WO[(2 * HREAL + e) * DMODEL + dm] + WO[(3 * HREAL + e) * DMODEL + dm];
    }
    wot[dm * HP + e] = f2bf(v);
  }
}

// ---------------- projections: X[16384,200] @ WT^T -> bf16 [16384,64] --------
// mode 0: q->Qp (scaled), 1: k->Kp, 2: v->VpT (transposed store [B][64][S])
__global__ __launch_bounds__(256) void proj_kernel(
    const float* __restrict__ q, const float* __restrict__ k, const float* __restrict__ v,
    const short* __restrict__ wqt, const short* __restrict__ wkt, const short* __restrict__ wvt,
    short* __restrict__ Qp, short* __restrict__ Kp, short* __restrict__ VpT) {
  const int mode = blockIdx.z;
  const float* X = (mode == 0) ? q : (mode == 1 ? k : v);
  const short* WT = (mode == 0) ? wqt : (mode == 1 ? wkt : wvt);
  const int lane = threadIdx.x & 63, wid = threadIdx.x >> 6;
  const int l15 = lane & 15, g = lane >> 4;
  const int sbase = blockIdx.x * 64 + wid * 16;
  const int row = sbase + l15;
  f4 acc[4] = {};
  for (int c = 0; c < 13; ++c) {
    int d0 = 16 * c + 4 * g;
    f4 a4 = {};
    if (d0 < DMODEL) a4 = *(const f4*)(X + (size_t)row * DMODEL + d0);
    s4 af;
#pragma unroll
    for (int j = 0; j < 4; ++j) af[j] = f2bf(a4[j]);
#pragma unroll
    for (int n = 0; n < 4; ++n) {
      s4 bf = *(const s4*)(WT + (16 * n + l15) * DMP + d0);
      acc[n] = __builtin_amdgcn_mfma_f32_16x16x16bf16_1k(af, bf, acc[n], 0, 0, 0);
    }
  }
  if (mode < 2) {
    short* OUT = (mode == 0) ? Qp : Kp;
#pragma unroll
    for (int n = 0; n < 4; ++n)
#pragma unroll
      for (int r = 0; r < 4; ++r) {
        int rr = sbase + 4 * g + r;
        OUT[rr * HP + 16 * n + l15] = f2bf(acc[n][r]);
      }
  } else {
#pragma unroll
    for (int n = 0; n < 4; ++n)
#pragma unroll
      for (int r = 0; r < 4; ++r) {
        int rr = sbase + 4 * g + r;
        int bb = rr >> 12, s = rr & 4095;
        VpT[((bb * HP) + 16 * n + l15) * SLEN + s] = f2bf(acc[n][r]);
      }
  }
}

// ---------------- flash attention, swapped-operand QK^T, KV-split ------------
// LDS content: linear dest, inverse-swizzled global source (involution xor of
// byte bits 4-6 with row&7). Reads apply the same xor -> conflict-free.
__global__ __launch_bounds__(256, 6) void attn_kernel(
    const short* __restrict__ Qp, const short* __restrict__ Kp,
    const short* __restrict__ VpT, float* __restrict__ Mp,
    float* __restrict__ Lp, float* __restrict__ Op) {
  __shared__ __align__(16) char Klds[KVB * 128];  // [key][128B], swizzled
  __shared__ __align__(16) char Vlds[HP * 128];   // [d][64 keys*2B], swizzled
  const int tid = threadIdx.x;
  const int lane = tid & 63, wid = tid >> 6;
  const int l15 = lane & 15, g = lane >> 4;
  const int b = blockIdx.y, z = blockIdx.z;
  const int nsplit = gridDim.z;
  const int qrow = blockIdx.x * 64 + wid * 16 + l15;
  const int ksw = (l15 & 7) << 4;

  // Q fragments (R1-proven 16x16x16_1k convention): elements 16c + 4g .. +3
  s4 qf[4];
  {
    const short* qptr = Qp + (size_t)(b * SLEN + qrow) * HP + 4 * g;
#pragma unroll
    for (int c = 0; c < 4; ++c) qf[c] = *(const s4*)(qptr + 16 * c);
  }

  // LDS read base offsets (bytes), loop-invariant; inner addr = base + tt*2048
  const int kr0 = l15 * 128 + ((8 * g) ^ ksw);
  const int kr1 = l15 * 128 + ((32 + 8 * g) ^ ksw);
  const int kr2 = l15 * 128 + ((64 + 8 * g) ^ ksw);
  const int kr3 = l15 * 128 + ((96 + 8 * g) ^ ksw);
  const int vb = l15 * 128 + ((8 * g) ^ ksw);

  // staging: linear LDS slot cj <- global slot ci = cj ^ (row&7)
  const int cj0 = tid, cj1 = tid + 256;
  const int ci0 = (cj0 ^ ((cj0 >> 3) & 7)) * 16;
  const int ci1 = (cj1 ^ ((cj1 >> 3) & 7)) * 16;
  const int d0 = cj0 >> 3, d1 = cj1 >> 3;
  const int ch0 = ((cj0 & 7) ^ (d0 & 7)) * 16;
  const int ch1 = ((cj1 & 7) ^ (d1 & 7)) * 16;

  const int kv0 = z * (SLEN / nsplit);
  const char* kp0 = (const char*)Kp + (size_t)(b * SLEN + kv0) * 128 + ci0;
  const char* kp1 = (const char*)Kp + (size_t)(b * SLEN + kv0) * 128 + ci1;
  const char* vp0 =
      (const char*)VpT + ((size_t)(b * HP + d0) * SLEN + kv0) * 2 + ch0;
  const char* vp1 =
      (const char*)VpT + ((size_t)(b * HP + d1) * SLEN + kv0) * 2 + ch1;

  f4 o[4] = {};
  float m = -1e30f, lsum = 0.f;
  const int nsteps = SLEN / nsplit / KVB;
  for (int step = 0; step < nsteps; ++step) {
    __syncthreads();
    {
      f4 k0 = *(const f4*)kp0;
      f4 k1 = *(const f4*)kp1;
      f4 v0 = *(const f4*)vp0;
      f4 v1 = *(const f4*)vp1;
      *(f4*)(Klds + tid * 16) = k0;
      *(f4*)(Klds + tid * 16 + 4096) = k1;
      *(f4*)(Vlds + tid * 16) = v0;
      *(f4*)(Vlds + tid * 16 + 4096) = v1;
      kp0 += KVB * 128;
      kp1 += KVB * 128;
      vp0 += KVB * 2;
      vp1 += KVB * 2;
    }
    __syncthreads();
#pragma unroll
    for (int tt = 0; tt < 4; ++tt) {
      // S^T tile [16 keys x 16 q] = K_tile . Q^T  (C: col=q=l15, row=key=4g+r)
      f4 st = {};
      {
        s4 kf0 = *(const s4*)(Klds + kr0 + tt * 2048);
        s4 kf1 = *(const s4*)(Klds + kr1 + tt * 2048);
        s4 kf2 = *(const s4*)(Klds + kr2 + tt * 2048);
        s4 kf3 = *(const s4*)(Klds + kr3 + tt * 2048);
        st = __builtin_amdgcn_mfma_f32_16x16x16bf16_1k(kf0, qf[0], st, 0, 0, 0);
        st = __builtin_amdgcn_mfma_f32_16x16x16bf16_1k(kf1, qf[1], st, 0, 0, 0);
        st = __builtin_amdgcn_mfma_f32_16x16x16bf16_1k(kf2, qf[2], st, 0, 0, 0);
        st = __builtin_amdgcn_mfma_f32_16x16x16bf16_1k(kf3, qf[3], st, 0, 0, 0);
      }
      float tmax = fmaxf(fmaxf(st[0], st[1]), fmaxf(st[2], st[3]));
      if (__builtin_expect(__any(tmax > m + 8.0f), 0)) {
        float t = fmaxf(tmax, __shfl_xor(tmax, 16));
        t = fmaxf(t, __shfl_xor(t, 32));
        t = fmaxf(t, m);
        float corr = fexp2(m - t);
        lsum *= corr;
#pragma unroll
        for (int n = 0; n < 4; ++n) {
          o[n][0] *= corr;
          o[n][1] *= corr;
          o[n][2] *= corr;
          o[n][3] *= corr;
        }
        m = t;
      }
      float p0 = fexp2(st[0] - m), p1 = fexp2(st[1] - m);
      float p2 = fexp2(st[2] - m), p3 = fexp2(st[3] - m);
      lsum += (p0 + p1) + (p2 + p3);
      union {
        unsigned u[2];
        s4 s;
      } pu;
      asm("v_cvt_pk_bf16_f32 %0, %1, %2" : "=v"(pu.u[0]) : "v"(p0), "v"(p1));
      asm("v_cvt_pk_bf16_f32 %0, %1, %2" : "=v"(pu.u[1]) : "v"(p2), "v"(p3));
      s4 pf = pu.s;
      // O^T[d][q] += V^T . P  (P already in B-frag layout: col=q=l15, k=4g+r)
      const char* vrow = Vlds + (vb ^ (tt << 5));
#pragma unroll
      for (int n = 0; n < 4; ++n) {
        s4 vf = *(const s4*)(vrow + n * 2048);
        o[n] = __builtin_amdgcn_mfma_f32_16x16x16bf16_1k(vf, pf, o[n], 0, 0, 0);
      }
    }
  }
  lsum += __shfl_xor(lsum, 16);
  lsum += __shfl_xor(lsum, 32);
  const int rowg = b * SLEN + qrow;
  const int NR = NB * SLEN;
  if (lane < 16) {
    Mp[z * NR + rowg] = m;
    Lp[z * NR + rowg] = lsum;
  }
  float* op = Op + ((size_t)z * NR + rowg) * HP;
#pragma unroll
  for (int n = 0; n < 4; ++n) *(f4*)(op + 16 * n + 4 * g) = o[n];
}

// ---------------- merge the KV-split partials, normalize, -> bf16 ------------
__global__ __launch_bounds__(256) void combine_kernel(
    const float* __restrict__ Mp, const float* __restrict__ Lp,
    const float* __restrict__ Op, short* __restrict__ Ob, int nsplit) {
  int id = blockIdx.x * 256 + threadIdx.x;  // 262144 total
  int rowg = id >> 4;
  int dc = id & 15;
  const int NR = NB * SLEN;
  float mm = -1e30f;
  for (int s = 0; s < nsplit; ++s) mm = fmaxf(mm, Mp[s * NR + rowg]);
  float L = 0.f;
  f4 acc = {};
  for (int s = 0; s < nsplit; ++s) {
    float w = fexp2(Mp[s * NR + rowg] - mm);
    L += w * Lp[s * NR + rowg];
    f4 vv = *(const f4*)(Op + ((size_t)s * NR + rowg) * HP + dc * 4);
    acc[0] += w * vv[0];
    acc[1] += w * vv[1];
    acc[2] += w * vv[2];
    acc[3] += w * vv[3];
  }
  float inv = 1.0f / L;
  s4 ov;
#pragma unroll
  for (int i = 0; i < 4; ++i) ov[i] = f2bf(acc[i] * inv);
  *(s4*)(Ob + (size_t)rowg * HP + dc * 4) = ov;
}

// ---------------- out-projection: O[16384,64(bf16)] @ WOsum -> out fp32 ------
__global__ __launch_bounds__(256) void outproj_kernel(
    const short* __restrict__ Ob, const short* __restrict__ wot,
    float* __restrict__ out) {
  const int lane = threadIdx.x & 63, wid = threadIdx.x >> 6;
  const int l15 = lane & 15, g = lane >> 4;
  const int sbase = blockIdx.x * 64 + wid * 16;
  s4 af[4];
  const short* arow = Ob + (size_t)(sbase + l15) * HP + 4 * g;
#pragma unroll
  for (int c = 0; c < 4; ++c) af[c] = *(const s4*)(arow + 16 * c);
  for (int n = 0; n < 13; ++n) {
    f4 acc = {};
    const short* brow = wot + (16 * n + l15) * HP + 4 * g;
#pragma unroll
    for (int c = 0; c < 4; ++c) {
      s4 bf = *(const s4*)(brow + 16 * c);
      acc = __builtin_amdgcn_mfma_f32_16x16x16bf16_1k(af[c], bf, acc, 0, 0, 0);
    }
    int dm = 16 * n + l15;
    if (dm < DMODEL) {
#pragma unroll
      for (int r = 0; r < 4; ++r) {
        int rr = sbase + 4 * g + r;
        out[(size_t)rr * DMODEL + dm] = acc[r];
      }
    }
  }
}

extern "C" void kernel_launch(void* const* d_in, const int* in_sizes, int n_in,
                              void* d_out, int out_size, void* d_ws, size_t ws_size,
                              hipStream_t stream) {
  const float* q = (const float*)d_in[0];
  const float* k = (const float*)d_in[1];
  const float* v = (const float*)d_in[2];
  const float* WQ = (const float*)d_in[3];
  const float* WK = (const float*)d_in[4];
  const float* WV = (const float*)d_in[5];
  const float* WO = (const float*)d_in[6];
  float* out = (float*)d_out;
  char* ws = (char*)d_ws;

  const size_t MB2 = 2097152;  // 16384*64*2 bytes
  const size_t NR = (size_t)NB * SLEN;
  // choose KV-split by available workspace
  size_t need8 = 131072 + 4 * MB2 + 8 * NR * 4 * 2 + 8 * NR * HP * 4;
  int nsplit = (ws_size >= need8) ? 8 : 4;

  short* wqt = (short*)(ws + 0);
  short* wkt = (short*)(ws + 32768);
  short* wvt = (short*)(ws + 65536);
  short* wot = (short*)(ws + 98304);
  short* Qp = (short*)(ws + 131072);
  short* Kp = (short*)(ws + 131072 + MB2);
  short* VpT = (short*)(ws + 131072 + 2 * MB2);
  short* Ob = (short*)(ws + 131072 + 3 * MB2);
  float* Mp = (float*)(ws + 131072 + 4 * MB2);
  float* Lp = Mp + nsplit * NR;
  float* Op = Lp + nsplit * NR;

  prep_weights<<<dim3(208), dim3(256), 0, stream>>>(WQ, WK, WV, WO, wqt, wkt, wvt, wot);
  proj_kernel<<<dim3(256, 1, 3), dim3(256), 0, stream>>>(q, k, v, wqt, wkt, wvt, Qp, Kp, VpT);
  attn_kernel<<<dim3(64, NB, nsplit), dim3(256), 0, stream>>>(Qp, Kp, VpT, Mp, Lp, Op);
  combine_kernel<<<dim3(1024), dim3(256), 0, stream>>>(Mp, Lp, Op, Ob, nsplit);
  outproj_kernel<<<dim3(256), dim3(256), 0, stream>>>(Ob, wot, out);
}

// Round 6
// 76.382 us; speedup vs baseline: 1.2997x; 1.0635x over previous
//
#include <hip/hip_runtime.h>
#include <hip/hip_bf16.h>

// Problem: B=4, S=4096, D_MODEL=200, head=50 (padded to 64), out fp32.
// Pipeline: prep_weights -> proj (MFMA) -> flash attn (MFMA, KV-split,
//           T14 reg-prefetch) -> fused combine+outproj (MFMA).

typedef short s4 __attribute__((ext_vector_type(4)));
typedef float f4 __attribute__((ext_vector_type(4)));

#define SLEN 4096
#define NB 4
#define DMODEL 200
#define HREAL 50
#define HP 64
#define DMP 208
#define KVB 64
// (1/sqrt(50)) * log2(e) folded into WQ so softmax uses exp2 (v_exp_f32)
#define QSCALE 0.20402789f

__device__ __forceinline__ short f2bf(float f) {
  unsigned u = __builtin_bit_cast(unsigned, f);
  u += 0x7FFFu + ((u >> 16) & 1u);
  return (short)(u >> 16);
}

__device__ __forceinline__ float fexp2(float x) { return __builtin_amdgcn_exp2f(x); }

// ---------------- weight prep: transpose+pad+bf16 (and sum WO head blocks) ---
__global__ void prep_weights(const float* __restrict__ WQ, const float* __restrict__ WK,
                             const float* __restrict__ WV, const float* __restrict__ WO,
                             short* __restrict__ wqt, short* __restrict__ wkt,
                             short* __restrict__ wvt, short* __restrict__ wot) {
  int id = blockIdx.x * 256 + threadIdx.x;
  const int NW = HP * DMP;  // 13312
  if (id < 3 * NW) {
    int which = id / NW, rem = id % NW;
    int e = rem / DMP, d = rem % DMP;
    float v = 0.f;
    if (e < HREAL && d < DMODEL) {
      const float* W = (which == 0) ? WQ : (which == 1 ? WK : WV);
      v = W[d * HREAL + e];
      if (which == 0) v *= QSCALE;
    }
    short* T = (which == 0) ? wqt : (which == 1 ? wkt : wvt);
    T[e * DMP + d] = f2bf(v);
  } else if (id < 4 * NW) {
    int rem = id - 3 * NW;
    int dm = rem / HP, e = rem % HP;
    float v = 0.f;
    if (dm < DMODEL && e < HREAL) {
      v = WO[(e)*DMODEL + dm] + WO[(HREAL + e) * DMODEL + dm] +
          WO[(2 * HREAL + e) * DMODEL + dm] + WO[(3 * HREAL + e) * DMODEL + dm];
    }
    wot[dm * HP + e] = f2bf(v);
  }
}

// ---------------- projections: X[16384,200] @ WT^T -> bf16 [16384,64] --------
// mode 0: q->Qp (scaled), 1: k->Kp, 2: v->VpT (transposed store [B][64][S])
__global__ __launch_bounds__(256) void proj_kernel(
    const float* __restrict__ q, const float* __restrict__ k, const float* __restrict__ v,
    const short* __restrict__ wqt, const short* __restrict__ wkt, const short* __restrict__ wvt,
    short* __restrict__ Qp, short* __restrict__ Kp, short* __restrict__ VpT) {
  const int mode = blockIdx.z;
  const float* X = (mode == 0) ? q : (mode == 1 ? k : v);
  const short* WT = (mode == 0) ? wqt : (mode == 1 ? wkt : wvt);
  const int lane = threadIdx.x & 63, wid = threadIdx.x >> 6;
  const int l15 = lane & 15, g = lane >> 4;
  const int sbase = blockIdx.x * 64 + wid * 16;
  const int row = sbase + l15;
  f4 acc[4] = {};
  for (int c = 0; c < 13; ++c) {
    int d0 = 16 * c + 4 * g;
    f4 a4 = {};
    if (d0 < DMODEL) a4 = *(const f4*)(X + (size_t)row * DMODEL + d0);
    s4 af;
#pragma unroll
    for (int j = 0; j < 4; ++j) af[j] = f2bf(a4[j]);
#pragma unroll
    for (int n = 0; n < 4; ++n) {
      s4 bf = *(const s4*)(WT + (16 * n + l15) * DMP + d0);
      acc[n] = __builtin_amdgcn_mfma_f32_16x16x16bf16_1k(af, bf, acc[n], 0, 0, 0);
    }
  }
  if (mode < 2) {
    short* OUT = (mode == 0) ? Qp : Kp;
#pragma unroll
    for (int n = 0; n < 4; ++n)
#pragma unroll
      for (int r = 0; r < 4; ++r) {
        int rr = sbase + 4 * g + r;
        OUT[rr * HP + 16 * n + l15] = f2bf(acc[n][r]);
      }
  } else {
#pragma unroll
    for (int n = 0; n < 4; ++n)
#pragma unroll
      for (int r = 0; r < 4; ++r) {
        int rr = sbase + 4 * g + r;
        int bb = rr >> 12, s = rr & 4095;
        VpT[((bb * HP) + 16 * n + l15) * SLEN + s] = f2bf(acc[n][r]);
      }
  }
}

// ---------------- flash attention, swapped-operand QK^T, KV-split ------------
// LDS content: linear dest, inverse-swizzled global source (involution xor of
// byte bits 4-6 with row&7). Reads apply the same xor -> conflict-free.
// Layout/addressing byte-identical to the R4-proven kernel (KVB=64); only the
// load issue point moved (T14): prologue-load, then per-step write LDS ->
// barrier -> issue next-tile loads -> compute.
__global__ __launch_bounds__(256, 6) void attn_kernel(
    const short* __restrict__ Qp, const short* __restrict__ Kp,
    const short* __restrict__ VpT, float* __restrict__ Mp,
    float* __restrict__ Lp, float* __restrict__ Op) {
  __shared__ __align__(16) char Klds[KVB * 128];  // [key][128B], swizzled
  __shared__ __align__(16) char Vlds[HP * 128];   // [d][64 keys*2B], swizzled
  const int tid = threadIdx.x;
  const int lane = tid & 63, wid = tid >> 6;
  const int l15 = lane & 15, g = lane >> 4;
  const int b = blockIdx.y, z = blockIdx.z;
  const int nsplit = gridDim.z;
  const int qrow = blockIdx.x * 64 + wid * 16 + l15;
  const int ksw = (l15 & 7) << 4;

  // Q fragments (16x16x16_1k convention): elements 16c + 4g .. +3
  s4 qf[4];
  {
    const short* qptr = Qp + (size_t)(b * SLEN + qrow) * HP + 4 * g;
#pragma unroll
    for (int c = 0; c < 4; ++c) qf[c] = *(const s4*)(qptr + 16 * c);
  }

  // LDS read base offsets (bytes), loop-invariant; inner addr = base + tt*2048
  const int kr0 = l15 * 128 + ((8 * g) ^ ksw);
  const int kr1 = l15 * 128 + ((32 + 8 * g) ^ ksw);
  const int kr2 = l15 * 128 + ((64 + 8 * g) ^ ksw);
  const int kr3 = l15 * 128 + ((96 + 8 * g) ^ ksw);
  const int vb = l15 * 128 + ((8 * g) ^ ksw);

  // staging: linear LDS slot cj <- global slot ci = cj ^ (row&7)
  const int cj0 = tid, cj1 = tid + 256;
  const int ci0 = (cj0 ^ ((cj0 >> 3) & 7)) * 16;
  const int ci1 = (cj1 ^ ((cj1 >> 3) & 7)) * 16;
  const int d0 = cj0 >> 3, d1 = cj1 >> 3;
  const int ch0 = ((cj0 & 7) ^ (d0 & 7)) * 16;
  const int ch1 = ((cj1 & 7) ^ (d1 & 7)) * 16;

  const int kv0 = z * (SLEN / nsplit);
  const char* kp0 = (const char*)Kp + (size_t)(b * SLEN + kv0) * 128 + ci0;
  const char* kp1 = (const char*)Kp + (size_t)(b * SLEN + kv0) * 128 + ci1;
  const char* vp0 =
      (const char*)VpT + ((size_t)(b * HP + d0) * SLEN + kv0) * 2 + ch0;
  const char* vp1 =
      (const char*)VpT + ((size_t)(b * HP + d1) * SLEN + kv0) * 2 + ch1;

  // T14 prologue: load tile 0 into regs
  f4 rk0 = *(const f4*)kp0;
  f4 rk1 = *(const f4*)kp1;
  f4 rv0 = *(const f4*)vp0;
  f4 rv1 = *(const f4*)vp1;
  kp0 += KVB * 128;
  kp1 += KVB * 128;
  vp0 += KVB * 2;
  vp1 += KVB * 2;

  f4 o[4] = {};
  float m = -1e30f, lsum = 0.f;
  const int nsteps = SLEN / nsplit / KVB;
  for (int step = 0; step < nsteps; ++step) {
    __syncthreads();
    *(f4*)(Klds + tid * 16) = rk0;
    *(f4*)(Klds + tid * 16 + 4096) = rk1;
    *(f4*)(Vlds + tid * 16) = rv0;
    *(f4*)(Vlds + tid * 16 + 4096) = rv1;
    __syncthreads();
    if (step + 1 < nsteps) {
      rk0 = *(const f4*)kp0;
      rk1 = *(const f4*)kp1;
      rv0 = *(const f4*)vp0;
      rv1 = *(const f4*)vp1;
      kp0 += KVB * 128;
      kp1 += KVB * 128;
      vp0 += KVB * 2;
      vp1 += KVB * 2;
    }
#pragma unroll
    for (int tt = 0; tt < 4; ++tt) {
      // S^T tile [16 keys x 16 q] = K_tile . Q^T  (C: col=q=l15, row=key=4g+r)
      f4 st = {};
      {
        s4 kf0 = *(const s4*)(Klds + kr0 + tt * 2048);
        s4 kf1 = *(const s4*)(Klds + kr1 + tt * 2048);
        s4 kf2 = *(const s4*)(Klds + kr2 + tt * 2048);
        s4 kf3 = *(const s4*)(Klds + kr3 + tt * 2048);
        st = __builtin_amdgcn_mfma_f32_16x16x16bf16_1k(kf0, qf[0], st, 0, 0, 0);
        st = __builtin_amdgcn_mfma_f32_16x16x16bf16_1k(kf1, qf[1], st, 0, 0, 0);
        st = __builtin_amdgcn_mfma_f32_16x16x16bf16_1k(kf2, qf[2], st, 0, 0, 0);
        st = __builtin_amdgcn_mfma_f32_16x16x16bf16_1k(kf3, qf[3], st, 0, 0, 0);
      }
      float tmax = fmaxf(fmaxf(st[0], st[1]), fmaxf(st[2], st[3]));
      if (__builtin_expect(__any(tmax > m + 8.0f), 0)) {
        float t = fmaxf(tmax, __shfl_xor(tmax, 16));
        t = fmaxf(t, __shfl_xor(t, 32));
        t = fmaxf(t, m);
        float corr = fexp2(m - t);
        lsum *= corr;
#pragma unroll
        for (int n = 0; n < 4; ++n) {
          o[n][0] *= corr;
          o[n][1] *= corr;
          o[n][2] *= corr;
          o[n][3] *= corr;
        }
        m = t;
      }
      float p0 = fexp2(st[0] - m), p1 = fexp2(st[1] - m);
      float p2 = fexp2(st[2] - m), p3 = fexp2(st[3] - m);
      lsum += (p0 + p1) + (p2 + p3);
      union {
        unsigned u[2];
        s4 s;
      } pu;
      asm("v_cvt_pk_bf16_f32 %0, %1, %2" : "=v"(pu.u[0]) : "v"(p0), "v"(p1));
      asm("v_cvt_pk_bf16_f32 %0, %1, %2" : "=v"(pu.u[1]) : "v"(p2), "v"(p3));
      s4 pf = pu.s;
      // O^T[d][q] += V^T . P  (P already in B-frag layout: col=q=l15, k=4g+r)
      const char* vrow = Vlds + (vb ^ (tt << 5));
#pragma unroll
      for (int n = 0; n < 4; ++n) {
        s4 vf = *(const s4*)(vrow + n * 2048);
        o[n] = __builtin_amdgcn_mfma_f32_16x16x16bf16_1k(vf, pf, o[n], 0, 0, 0);
      }
    }
  }
  lsum += __shfl_xor(lsum, 16);
  lsum += __shfl_xor(lsum, 32);
  const int rowg = b * SLEN + qrow;
  const int NR = NB * SLEN;
  if (lane < 16) {
    Mp[z * NR + rowg] = m;
    Lp[z * NR + rowg] = lsum;
  }
  float* op = Op + ((size_t)z * NR + rowg) * HP;
#pragma unroll
  for (int n = 0; n < 4; ++n) *(f4*)(op + 16 * n + 4 * g) = o[n];
}

// ------- fused: merge KV-split partials + normalize + out-projection ---------
template <int NSPLIT>
__global__ __launch_bounds__(256) void combineproj_kernel(
    const float* __restrict__ Mp, const float* __restrict__ Lp,
    const float* __restrict__ Op, const short* __restrict__ wot,
    float* __restrict__ out) {
  const int lane = threadIdx.x & 63, wid = threadIdx.x >> 6;
  const int l15 = lane & 15, g = lane >> 4;
  const int sbase = blockIdx.x * 64 + wid * 16;
  const int row = sbase + l15;
  const int NR = NB * SLEN;
  float mm = -1e30f;
#pragma unroll
  for (int s = 0; s < NSPLIT; ++s) mm = fmaxf(mm, Mp[s * NR + row]);
  float w[NSPLIT];
  float L = 0.f;
#pragma unroll
  for (int s = 0; s < NSPLIT; ++s) {
    w[s] = fexp2(Mp[s * NR + row] - mm);
    L += w[s] * Lp[s * NR + row];
  }
  float inv = 1.0f / L;
  s4 af[4];
#pragma unroll
  for (int c = 0; c < 4; ++c) {
    f4 acc = {};
#pragma unroll
    for (int s = 0; s < NSPLIT; ++s) {
      f4 vv = *(const f4*)(Op + ((size_t)s * NR + row) * HP + 16 * c + 4 * g);
      acc[0] += w[s] * vv[0];
      acc[1] += w[s] * vv[1];
      acc[2] += w[s] * vv[2];
      acc[3] += w[s] * vv[3];
    }
#pragma unroll
    for (int r = 0; r < 4; ++r) af[c][r] = f2bf(acc[r] * inv);
  }
  for (int n = 0; n < 13; ++n) {
    f4 acc = {};
    const short* brow = wot + (16 * n + l15) * HP + 4 * g;
#pragma unroll
    for (int c = 0; c < 4; ++c) {
      s4 bf = *(const s4*)(brow + 16 * c);
      acc = __builtin_amdgcn_mfma_f32_16x16x16bf16_1k(af[c], bf, acc, 0, 0, 0);
    }
    int dm = 16 * n + l15;
    if (dm < DMODEL) {
#pragma unroll
      for (int r = 0; r < 4; ++r) {
        int rr = sbase + 4 * g + r;
        out[(size_t)rr * DMODEL + dm] = acc[r];
      }
    }
  }
}

extern "C" void kernel_launch(void* const* d_in, const int* in_sizes, int n_in,
                              void* d_out, int out_size, void* d_ws, size_t ws_size,
                              hipStream_t stream) {
  const float* q = (const float*)d_in[0];
  const float* k = (const float*)d_in[1];
  const float* v = (const float*)d_in[2];
  const float* WQ = (const float*)d_in[3];
  const float* WK = (const float*)d_in[4];
  const float* WV = (const float*)d_in[5];
  const float* WO = (const float*)d_in[6];
  float* out = (float*)d_out;
  char* ws = (char*)d_ws;

  const size_t MB2 = 2097152;  // 16384*64*2 bytes
  const size_t NR = (size_t)NB * SLEN;
  // choose KV-split by available workspace
  size_t need8 = 131072 + 4 * MB2 + 8 * NR * 4 * 2 + 8 * NR * HP * 4;
  int nsplit = (ws_size >= need8) ? 8 : 4;

  short* wqt = (short*)(ws + 0);
  short* wkt = (short*)(ws + 32768);
  short* wvt = (short*)(ws + 65536);
  short* wot = (short*)(ws + 98304);
  short* Qp = (short*)(ws + 131072);
  short* Kp = (short*)(ws + 131072 + MB2);
  short* VpT = (short*)(ws + 131072 + 2 * MB2);
  float* Mp = (float*)(ws + 131072 + 4 * MB2);
  float* Lp = Mp + nsplit * NR;
  float* Op = Lp + nsplit * NR;

  prep_weights<<<dim3(208), dim3(256), 0, stream>>>(WQ, WK, WV, WO, wqt, wkt, wvt, wot);
  proj_kernel<<<dim3(256, 1, 3), dim3(256), 0, stream>>>(q, k, v, wqt, wkt, wvt, Qp, Kp, VpT);
  attn_kernel<<<dim3(64, NB, nsplit), dim3(256), 0, stream>>>(Qp, Kp, VpT, Mp, Lp, Op);
  if (nsplit == 8)
    combineproj_kernel<8><<<dim3(256), dim3(256), 0, stream>>>(Mp, Lp, Op, wot, out);
  else
    combineproj_kernel<4><<<dim3(256), dim3(256), 0, stream>>>(Mp, Lp, Op, wot, out);
}

// Round 7
// 73.212 us; speedup vs baseline: 1.3560x; 1.0433x over previous
//
#include <hip/hip_runtime.h>
#include <hip/hip_bf16.h>

// Problem: B=4, S=4096, D_MODEL=200, head=50 (padded to 64), out fp32.
// Pipeline: prep_weights -> proj (MFMA) -> flash attn (MFMA, KV-split,
//           T14 reg-prefetch, 2 q-tiles/wave, T5 setprio) -> fused
//           combine+outproj (MFMA).

typedef short s4 __attribute__((ext_vector_type(4)));
typedef float f4 __attribute__((ext_vector_type(4)));

#define SLEN 4096
#define NB 4
#define DMODEL 200
#define HREAL 50
#define HP 64
#define DMP 208
#define KVB 64
// (1/sqrt(50)) * log2(e) folded into WQ so softmax uses exp2 (v_exp_f32)
#define QSCALE 0.20402789f

__device__ __forceinline__ short f2bf(float f) {
  unsigned u = __builtin_bit_cast(unsigned, f);
  u += 0x7FFFu + ((u >> 16) & 1u);
  return (short)(u >> 16);
}

__device__ __forceinline__ float fexp2(float x) { return __builtin_amdgcn_exp2f(x); }

// ---------------- weight prep: transpose+pad+bf16 (and sum WO head blocks) ---
__global__ void prep_weights(const float* __restrict__ WQ, const float* __restrict__ WK,
                             const float* __restrict__ WV, const float* __restrict__ WO,
                             short* __restrict__ wqt, short* __restrict__ wkt,
                             short* __restrict__ wvt, short* __restrict__ wot) {
  int id = blockIdx.x * 256 + threadIdx.x;
  const int NW = HP * DMP;  // 13312
  if (id < 3 * NW) {
    int which = id / NW, rem = id % NW;
    int e = rem / DMP, d = rem % DMP;
    float v = 0.f;
    if (e < HREAL && d < DMODEL) {
      const float* W = (which == 0) ? WQ : (which == 1 ? WK : WV);
      v = W[d * HREAL + e];
      if (which == 0) v *= QSCALE;
    }
    short* T = (which == 0) ? wqt : (which == 1 ? wkt : wvt);
    T[e * DMP + d] = f2bf(v);
  } else if (id < 4 * NW) {
    int rem = id - 3 * NW;
    int dm = rem / HP, e = rem % HP;
    float v = 0.f;
    if (dm < DMODEL && e < HREAL) {
      v = WO[(e)*DMODEL + dm] + WO[(HREAL + e) * DMODEL + dm] +
          WO[(2 * HREAL + e) * DMODEL + dm] + WO[(3 * HREAL + e) * DMODEL + dm];
    }
    wot[dm * HP + e] = f2bf(v);
  }
}

// ---------------- projections: X[16384,200] @ WT^T -> bf16 [16384,64] --------
// mode 0: q->Qp (scaled), 1: k->Kp, 2: v->VpT (transposed store [B][64][S])
__global__ __launch_bounds__(256) void proj_kernel(
    const float* __restrict__ q, const float* __restrict__ k, const float* __restrict__ v,
    const short* __restrict__ wqt, const short* __restrict__ wkt, const short* __restrict__ wvt,
    short* __restrict__ Qp, short* __restrict__ Kp, short* __restrict__ VpT) {
  const int mode = blockIdx.z;
  const float* X = (mode == 0) ? q : (mode == 1 ? k : v);
  const short* WT = (mode == 0) ? wqt : (mode == 1 ? wkt : wvt);
  const int lane = threadIdx.x & 63, wid = threadIdx.x >> 6;
  const int l15 = lane & 15, g = lane >> 4;
  const int sbase = blockIdx.x * 64 + wid * 16;
  const int row = sbase + l15;
  f4 acc[4] = {};
  for (int c = 0; c < 13; ++c) {
    int d0 = 16 * c + 4 * g;
    f4 a4 = {};
    if (d0 < DMODEL) a4 = *(const f4*)(X + (size_t)row * DMODEL + d0);
    s4 af;
#pragma unroll
    for (int j = 0; j < 4; ++j) af[j] = f2bf(a4[j]);
#pragma unroll
    for (int n = 0; n < 4; ++n) {
      s4 bf = *(const s4*)(WT + (16 * n + l15) * DMP + d0);
      acc[n] = __builtin_amdgcn_mfma_f32_16x16x16bf16_1k(af, bf, acc[n], 0, 0, 0);
    }
  }
  if (mode < 2) {
    short* OUT = (mode == 0) ? Qp : Kp;
#pragma unroll
    for (int n = 0; n < 4; ++n)
#pragma unroll
      for (int r = 0; r < 4; ++r) {
        int rr = sbase + 4 * g + r;
        OUT[rr * HP + 16 * n + l15] = f2bf(acc[n][r]);
      }
  } else {
#pragma unroll
    for (int n = 0; n < 4; ++n)
#pragma unroll
      for (int r = 0; r < 4; ++r) {
        int rr = sbase + 4 * g + r;
        int bb = rr >> 12, s = rr & 4095;
        VpT[((bb * HP) + 16 * n + l15) * SLEN + s] = f2bf(acc[n][r]);
      }
  }
}

// ---------------- flash attention, swapped-operand QK^T, KV-split ------------
// LDS content: linear dest, inverse-swizzled global source (involution xor of
// byte bits 4-6 with row&7). Reads apply the same xor -> conflict-free.
// 2 q-tiles per wave (rows qbase & qbase+16): K/V LDS reads + staging shared,
// independent MFMA/softmax chains double latency-hiding ILP.
__global__ __launch_bounds__(256, 4) void attn_kernel(
    const short* __restrict__ Qp, const short* __restrict__ Kp,
    const short* __restrict__ VpT, float* __restrict__ Mp,
    float* __restrict__ Lp, float* __restrict__ Op) {
  __shared__ __align__(16) char Klds[KVB * 128];  // [key][128B], swizzled
  __shared__ __align__(16) char Vlds[HP * 128];   // [d][64 keys*2B], swizzled
  const int tid = threadIdx.x;
  const int lane = tid & 63, wid = tid >> 6;
  const int l15 = lane & 15, g = lane >> 4;
  const int b = blockIdx.y, z = blockIdx.z;
  const int nsplit = gridDim.z;
  const int qrowA = blockIdx.x * 128 + wid * 32 + l15;
  const int qrowB = qrowA + 16;
  const int ksw = (l15 & 7) << 4;

  // Q fragments (16x16x16_1k convention): elements 16c + 4g .. +3
  s4 qfA[4], qfB[4];
  {
    const short* qpa = Qp + (size_t)(b * SLEN + qrowA) * HP + 4 * g;
    const short* qpb = Qp + (size_t)(b * SLEN + qrowB) * HP + 4 * g;
#pragma unroll
    for (int c = 0; c < 4; ++c) {
      qfA[c] = *(const s4*)(qpa + 16 * c);
      qfB[c] = *(const s4*)(qpb + 16 * c);
    }
  }

  // LDS read base offsets (bytes), loop-invariant; inner addr = base + tt*2048
  const int kr0 = l15 * 128 + ((8 * g) ^ ksw);
  const int kr1 = l15 * 128 + ((32 + 8 * g) ^ ksw);
  const int kr2 = l15 * 128 + ((64 + 8 * g) ^ ksw);
  const int kr3 = l15 * 128 + ((96 + 8 * g) ^ ksw);
  const int vb = l15 * 128 + ((8 * g) ^ ksw);

  // staging: linear LDS slot cj <- global slot ci = cj ^ (row&7)
  const int cj0 = tid, cj1 = tid + 256;
  const int ci0 = (cj0 ^ ((cj0 >> 3) & 7)) * 16;
  const int ci1 = (cj1 ^ ((cj1 >> 3) & 7)) * 16;
  const int d0 = cj0 >> 3, d1 = cj1 >> 3;
  const int ch0 = ((cj0 & 7) ^ (d0 & 7)) * 16;
  const int ch1 = ((cj1 & 7) ^ (d1 & 7)) * 16;

  const int kv0 = z * (SLEN / nsplit);
  const char* kp0 = (const char*)Kp + (size_t)(b * SLEN + kv0) * 128 + ci0;
  const char* kp1 = (const char*)Kp + (size_t)(b * SLEN + kv0) * 128 + ci1;
  const char* vp0 =
      (const char*)VpT + ((size_t)(b * HP + d0) * SLEN + kv0) * 2 + ch0;
  const char* vp1 =
      (const char*)VpT + ((size_t)(b * HP + d1) * SLEN + kv0) * 2 + ch1;

  // T14 prologue: load tile 0 into regs
  f4 rk0 = *(const f4*)kp0;
  f4 rk1 = *(const f4*)kp1;
  f4 rv0 = *(const f4*)vp0;
  f4 rv1 = *(const f4*)vp1;
  kp0 += KVB * 128;
  kp1 += KVB * 128;
  vp0 += KVB * 2;
  vp1 += KVB * 2;

  f4 oA[4] = {}, oB[4] = {};
  float mA = -1e30f, lsumA = 0.f;
  float mB = -1e30f, lsumB = 0.f;
  const int nsteps = SLEN / nsplit / KVB;
  for (int step = 0; step < nsteps; ++step) {
    __syncthreads();
    *(f4*)(Klds + tid * 16) = rk0;
    *(f4*)(Klds + tid * 16 + 4096) = rk1;
    *(f4*)(Vlds + tid * 16) = rv0;
    *(f4*)(Vlds + tid * 16 + 4096) = rv1;
    __syncthreads();
    if (step + 1 < nsteps) {
      rk0 = *(const f4*)kp0;
      rk1 = *(const f4*)kp1;
      rv0 = *(const f4*)vp0;
      rv1 = *(const f4*)vp1;
      kp0 += KVB * 128;
      kp1 += KVB * 128;
      vp0 += KVB * 2;
      vp1 += KVB * 2;
    }
#pragma unroll
    for (int tt = 0; tt < 4; ++tt) {
      // S^T tile [16 keys x 16 q] = K_tile . Q^T  (C: col=q=l15, row=key=4g+r)
      f4 stA = {}, stB = {};
      {
        s4 kf0 = *(const s4*)(Klds + kr0 + tt * 2048);
        s4 kf1 = *(const s4*)(Klds + kr1 + tt * 2048);
        s4 kf2 = *(const s4*)(Klds + kr2 + tt * 2048);
        s4 kf3 = *(const s4*)(Klds + kr3 + tt * 2048);
        __builtin_amdgcn_s_setprio(1);
        stA = __builtin_amdgcn_mfma_f32_16x16x16bf16_1k(kf0, qfA[0], stA, 0, 0, 0);
        stB = __builtin_amdgcn_mfma_f32_16x16x16bf16_1k(kf0, qfB[0], stB, 0, 0, 0);
        stA = __builtin_amdgcn_mfma_f32_16x16x16bf16_1k(kf1, qfA[1], stA, 0, 0, 0);
        stB = __builtin_amdgcn_mfma_f32_16x16x16bf16_1k(kf1, qfB[1], stB, 0, 0, 0);
        stA = __builtin_amdgcn_mfma_f32_16x16x16bf16_1k(kf2, qfA[2], stA, 0, 0, 0);
        stB = __builtin_amdgcn_mfma_f32_16x16x16bf16_1k(kf2, qfB[2], stB, 0, 0, 0);
        stA = __builtin_amdgcn_mfma_f32_16x16x16bf16_1k(kf3, qfA[3], stA, 0, 0, 0);
        stB = __builtin_amdgcn_mfma_f32_16x16x16bf16_1k(kf3, qfB[3], stB, 0, 0, 0);
        __builtin_amdgcn_s_setprio(0);
      }
      // ---- softmax A ----
      float tmaxA = fmaxf(fmaxf(stA[0], stA[1]), fmaxf(stA[2], stA[3]));
      if (__builtin_expect(__any(tmaxA > mA + 8.0f), 0)) {
        float t = fmaxf(tmaxA, __shfl_xor(tmaxA, 16));
        t = fmaxf(t, __shfl_xor(t, 32));
        t = fmaxf(t, mA);
        float corr = fexp2(mA - t);
        lsumA *= corr;
#pragma unroll
        for (int n = 0; n < 4; ++n) {
          oA[n][0] *= corr; oA[n][1] *= corr; oA[n][2] *= corr; oA[n][3] *= corr;
        }
        mA = t;
      }
      float pa0 = fexp2(stA[0] - mA), pa1 = fexp2(stA[1] - mA);
      float pa2 = fexp2(stA[2] - mA), pa3 = fexp2(stA[3] - mA);
      lsumA += (pa0 + pa1) + (pa2 + pa3);
      union { unsigned u[2]; s4 s; } puA;
      asm("v_cvt_pk_bf16_f32 %0, %1, %2" : "=v"(puA.u[0]) : "v"(pa0), "v"(pa1));
      asm("v_cvt_pk_bf16_f32 %0, %1, %2" : "=v"(puA.u[1]) : "v"(pa2), "v"(pa3));
      s4 pfA = puA.s;
      // ---- softmax B ----
      float tmaxB = fmaxf(fmaxf(stB[0], stB[1]), fmaxf(stB[2], stB[3]));
      if (__builtin_expect(__any(tmaxB > mB + 8.0f), 0)) {
        float t = fmaxf(tmaxB, __shfl_xor(tmaxB, 16));
        t = fmaxf(t, __shfl_xor(t, 32));
        t = fmaxf(t, mB);
        float corr = fexp2(mB - t);
        lsumB *= corr;
#pragma unroll
        for (int n = 0; n < 4; ++n) {
          oB[n][0] *= corr; oB[n][1] *= corr; oB[n][2] *= corr; oB[n][3] *= corr;
        }
        mB = t;
      }
      float pb0 = fexp2(stB[0] - mB), pb1 = fexp2(stB[1] - mB);
      float pb2 = fexp2(stB[2] - mB), pb3 = fexp2(stB[3] - mB);
      lsumB += (pb0 + pb1) + (pb2 + pb3);
      union { unsigned u[2]; s4 s; } puB;
      asm("v_cvt_pk_bf16_f32 %0, %1, %2" : "=v"(puB.u[0]) : "v"(pb0), "v"(pb1));
      asm("v_cvt_pk_bf16_f32 %0, %1, %2" : "=v"(puB.u[1]) : "v"(pb2), "v"(pb3));
      s4 pfB = puB.s;
      // O^T[d][q] += V^T . P  (P already in B-frag layout: col=q=l15, k=4g+r)
      const char* vrow = Vlds + (vb ^ (tt << 5));
      __builtin_amdgcn_s_setprio(1);
#pragma unroll
      for (int n = 0; n < 4; ++n) {
        s4 vf = *(const s4*)(vrow + n * 2048);
        oA[n] = __builtin_amdgcn_mfma_f32_16x16x16bf16_1k(vf, pfA, oA[n], 0, 0, 0);
        oB[n] = __builtin_amdgcn_mfma_f32_16x16x16bf16_1k(vf, pfB, oB[n], 0, 0, 0);
      }
      __builtin_amdgcn_s_setprio(0);
    }
  }
  lsumA += __shfl_xor(lsumA, 16);
  lsumA += __shfl_xor(lsumA, 32);
  lsumB += __shfl_xor(lsumB, 16);
  lsumB += __shfl_xor(lsumB, 32);
  const int rowgA = b * SLEN + qrowA;
  const int rowgB = b * SLEN + qrowB;
  const int NR = NB * SLEN;
  if (lane < 16) {
    Mp[z * NR + rowgA] = mA;
    Lp[z * NR + rowgA] = lsumA;
    Mp[z * NR + rowgB] = mB;
    Lp[z * NR + rowgB] = lsumB;
  }
  float* opA = Op + ((size_t)z * NR + rowgA) * HP;
  float* opB = Op + ((size_t)z * NR + rowgB) * HP;
#pragma unroll
  for (int n = 0; n < 4; ++n) {
    *(f4*)(opA + 16 * n + 4 * g) = oA[n];
    *(f4*)(opB + 16 * n + 4 * g) = oB[n];
  }
}

// ------- fused: merge KV-split partials + normalize + out-projection ---------
template <int NSPLIT>
__global__ __launch_bounds__(256) void combineproj_kernel(
    const float* __restrict__ Mp, const float* __restrict__ Lp,
    const float* __restrict__ Op, const short* __restrict__ wot,
    float* __restrict__ out) {
  const int lane = threadIdx.x & 63, wid = threadIdx.x >> 6;
  const int l15 = lane & 15, g = lane >> 4;
  const int sbase = blockIdx.x * 64 + wid * 16;
  const int row = sbase + l15;
  const int NR = NB * SLEN;
  float mm = -1e30f;
#pragma unroll
  for (int s = 0; s < NSPLIT; ++s) mm = fmaxf(mm, Mp[s * NR + row]);
  float w[NSPLIT];
  float L = 0.f;
#pragma unroll
  for (int s = 0; s < NSPLIT; ++s) {
    w[s] = fexp2(Mp[s * NR + row] - mm);
    L += w[s] * Lp[s * NR + row];
  }
  float inv = 1.0f / L;
  s4 af[4];
#pragma unroll
  for (int c = 0; c < 4; ++c) {
    f4 acc = {};
#pragma unroll
    for (int s = 0; s < NSPLIT; ++s) {
      f4 vv = *(const f4*)(Op + ((size_t)s * NR + row) * HP + 16 * c + 4 * g);
      acc[0] += w[s] * vv[0];
      acc[1] += w[s] * vv[1];
      acc[2] += w[s] * vv[2];
      acc[3] += w[s] * vv[3];
    }
#pragma unroll
    for (int r = 0; r < 4; ++r) af[c][r] = f2bf(acc[r] * inv);
  }
  for (int n = 0; n < 13; ++n) {
    f4 acc = {};
    const short* brow = wot + (16 * n + l15) * HP + 4 * g;
#pragma unroll
    for (int c = 0; c < 4; ++c) {
      s4 bf = *(const s4*)(brow + 16 * c);
      acc = __builtin_amdgcn_mfma_f32_16x16x16bf16_1k(af[c], bf, acc, 0, 0, 0);
    }
    int dm = 16 * n + l15;
    if (dm < DMODEL) {
#pragma unroll
      for (int r = 0; r < 4; ++r) {
        int rr = sbase + 4 * g + r;
        out[(size_t)rr * DMODEL + dm] = acc[r];
      }
    }
  }
}

extern "C" void kernel_launch(void* const* d_in, const int* in_sizes, int n_in,
                              void* d_out, int out_size, void* d_ws, size_t ws_size,
                              hipStream_t stream) {
  const float* q = (const float*)d_in[0];
  const float* k = (const float*)d_in[1];
  const float* v = (const float*)d_in[2];
  const float* WQ = (const float*)d_in[3];
  const float* WK = (const float*)d_in[4];
  const float* WV = (const float*)d_in[5];
  const float* WO = (const float*)d_in[6];
  float* out = (float*)d_out;
  char* ws = (char*)d_ws;

  const size_t MB2 = 2097152;  // 16384*64*2 bytes
  const size_t NR = (size_t)NB * SLEN;
  // choose KV-split by available workspace
  size_t need8 = 131072 + 4 * MB2 + 8 * NR * 4 * 2 + 8 * NR * HP * 4;
  int nsplit = (ws_size >= need8) ? 8 : 4;

  short* wqt = (short*)(ws + 0);
  short* wkt = (short*)(ws + 32768);
  short* wvt = (short*)(ws + 65536);
  short* wot = (short*)(ws + 98304);
  short* Qp = (short*)(ws + 131072);
  short* Kp = (short*)(ws + 131072 + MB2);
  short* VpT = (short*)(ws + 131072 + 2 * MB2);
  float* Mp = (float*)(ws + 131072 + 4 * MB2);
  float* Lp = Mp + nsplit * NR;
  float* Op = Lp + nsplit * NR;

  prep_weights<<<dim3(208), dim3(256), 0, stream>>>(WQ, WK, WV, WO, wqt, wkt, wvt, wot);
  proj_kernel<<<dim3(256, 1, 3), dim3(256), 0, stream>>>(q, k, v, wqt, wkt, wvt, Qp, Kp, VpT);
  attn_kernel<<<dim3(32, NB, nsplit), dim3(256), 0, stream>>>(Qp, Kp, VpT, Mp, Lp, Op);
  if (nsplit == 8)
    combineproj_kernel<8><<<dim3(256), dim3(256), 0, stream>>>(Mp, Lp, Op, wot, out);
  else
    combineproj_kernel<4><<<dim3(256), dim3(256), 0, stream>>>(Mp, Lp, Op, wot, out);
}

// Round 8
// 72.210 us; speedup vs baseline: 1.3748x; 1.0139x over previous
//
#include <hip/hip_runtime.h>
#include <hip/hip_bf16.h>

// Problem: B=4, S=4096, D_MODEL=200, head=50 (padded to 64), out fp32.
// Pipeline: prep_weights -> proj (MFMA) -> flash attn (MFMA, KV-split,
//           ping-pong LDS single-barrier pipeline, 2 q-tiles/wave, T5
//           setprio) -> fused combine+outproj (MFMA).

typedef short s4 __attribute__((ext_vector_type(4)));
typedef float f4 __attribute__((ext_vector_type(4)));

#define SLEN 4096
#define NB 4
#define DMODEL 200
#define HREAL 50
#define HP 64
#define DMP 208
#define KVB 64
// (1/sqrt(50)) * log2(e) folded into WQ so softmax uses exp2 (v_exp_f32)
#define QSCALE 0.20402789f

__device__ __forceinline__ short f2bf(float f) {
  unsigned u = __builtin_bit_cast(unsigned, f);
  u += 0x7FFFu + ((u >> 16) & 1u);
  return (short)(u >> 16);
}

__device__ __forceinline__ float fexp2(float x) { return __builtin_amdgcn_exp2f(x); }

// ---------------- weight prep: transpose+pad+bf16 (and sum WO head blocks) ---
__global__ void prep_weights(const float* __restrict__ WQ, const float* __restrict__ WK,
                             const float* __restrict__ WV, const float* __restrict__ WO,
                             short* __restrict__ wqt, short* __restrict__ wkt,
                             short* __restrict__ wvt, short* __restrict__ wot) {
  int id = blockIdx.x * 256 + threadIdx.x;
  const int NW = HP * DMP;  // 13312
  if (id < 3 * NW) {
    int which = id / NW, rem = id % NW;
    int e = rem / DMP, d = rem % DMP;
    float v = 0.f;
    if (e < HREAL && d < DMODEL) {
      const float* W = (which == 0) ? WQ : (which == 1 ? WK : WV);
      v = W[d * HREAL + e];
      if (which == 0) v *= QSCALE;
    }
    short* T = (which == 0) ? wqt : (which == 1 ? wkt : wvt);
    T[e * DMP + d] = f2bf(v);
  } else if (id < 4 * NW) {
    int rem = id - 3 * NW;
    int dm = rem / HP, e = rem % HP;
    float v = 0.f;
    if (dm < DMODEL && e < HREAL) {
      v = WO[(e)*DMODEL + dm] + WO[(HREAL + e) * DMODEL + dm] +
          WO[(2 * HREAL + e) * DMODEL + dm] + WO[(3 * HREAL + e) * DMODEL + dm];
    }
    wot[dm * HP + e] = f2bf(v);
  }
}

// ---------------- projections: X[16384,200] @ WT^T -> bf16 [16384,64] --------
// mode 0: q->Qp (scaled), 1: k->Kp, 2: v->VpT (transposed store [B][64][S])
__global__ __launch_bounds__(256) void proj_kernel(
    const float* __restrict__ q, const float* __restrict__ k, const float* __restrict__ v,
    const short* __restrict__ wqt, const short* __restrict__ wkt, const short* __restrict__ wvt,
    short* __restrict__ Qp, short* __restrict__ Kp, short* __restrict__ VpT) {
  const int mode = blockIdx.z;
  const float* X = (mode == 0) ? q : (mode == 1 ? k : v);
  const short* WT = (mode == 0) ? wqt : (mode == 1 ? wkt : wvt);
  const int lane = threadIdx.x & 63, wid = threadIdx.x >> 6;
  const int l15 = lane & 15, g = lane >> 4;
  const int sbase = blockIdx.x * 64 + wid * 16;
  const int row = sbase + l15;
  f4 acc[4] = {};
  for (int c = 0; c < 13; ++c) {
    int d0 = 16 * c + 4 * g;
    f4 a4 = {};
    if (d0 < DMODEL) a4 = *(const f4*)(X + (size_t)row * DMODEL + d0);
    s4 af;
#pragma unroll
    for (int j = 0; j < 4; ++j) af[j] = f2bf(a4[j]);
#pragma unroll
    for (int n = 0; n < 4; ++n) {
      s4 bf = *(const s4*)(WT + (16 * n + l15) * DMP + d0);
      acc[n] = __builtin_amdgcn_mfma_f32_16x16x16bf16_1k(af, bf, acc[n], 0, 0, 0);
    }
  }
  if (mode < 2) {
    short* OUT = (mode == 0) ? Qp : Kp;
#pragma unroll
    for (int n = 0; n < 4; ++n)
#pragma unroll
      for (int r = 0; r < 4; ++r) {
        int rr = sbase + 4 * g + r;
        OUT[rr * HP + 16 * n + l15] = f2bf(acc[n][r]);
      }
  } else {
#pragma unroll
    for (int n = 0; n < 4; ++n)
#pragma unroll
      for (int r = 0; r < 4; ++r) {
        int rr = sbase + 4 * g + r;
        int bb = rr >> 12, s = rr & 4095;
        VpT[((bb * HP) + 16 * n + l15) * SLEN + s] = f2bf(acc[n][r]);
      }
  }
}

// ---------------- flash attention, swapped-operand QK^T, KV-split ------------
// LDS content: linear dest, inverse-swizzled global source (involution xor of
// byte bits 4-6 with row&7). Reads apply the same xor -> conflict-free.
// Ping-pong double buffer: step s reads buf[s&1], writes buf[(s+1)&1] AFTER
// compute; single __syncthreads per step covers both hazards. Global loads
// for tile s+1 issue at step top -> latency hidden under compute.
__global__ __launch_bounds__(256, 4) void attn_kernel(
    const short* __restrict__ Qp, const short* __restrict__ Kp,
    const short* __restrict__ VpT, float* __restrict__ Mp,
    float* __restrict__ Lp, float* __restrict__ Op) {
  __shared__ __align__(16) char Klds[2][KVB * 128];  // 2 x 8KB, swizzled
  __shared__ __align__(16) char Vlds[2][HP * 128];   // 2 x 8KB, swizzled
  const int tid = threadIdx.x;
  const int lane = tid & 63, wid = tid >> 6;
  const int l15 = lane & 15, g = lane >> 4;
  const int b = blockIdx.y, z = blockIdx.z;
  const int nsplit = gridDim.z;
  const int qrowA = blockIdx.x * 128 + wid * 32 + l15;
  const int qrowB = qrowA + 16;
  const int ksw = (l15 & 7) << 4;

  // Q fragments (16x16x16_1k convention): elements 16c + 4g .. +3
  s4 qfA[4], qfB[4];
  {
    const short* qpa = Qp + (size_t)(b * SLEN + qrowA) * HP + 4 * g;
    const short* qpb = Qp + (size_t)(b * SLEN + qrowB) * HP + 4 * g;
#pragma unroll
    for (int c = 0; c < 4; ++c) {
      qfA[c] = *(const s4*)(qpa + 16 * c);
      qfB[c] = *(const s4*)(qpb + 16 * c);
    }
  }

  // LDS read base offsets (bytes), loop-invariant; inner addr = base + tt*2048
  const int kr0 = l15 * 128 + ((8 * g) ^ ksw);
  const int kr1 = l15 * 128 + ((32 + 8 * g) ^ ksw);
  const int kr2 = l15 * 128 + ((64 + 8 * g) ^ ksw);
  const int kr3 = l15 * 128 + ((96 + 8 * g) ^ ksw);
  const int vb = l15 * 128 + ((8 * g) ^ ksw);

  // staging: linear LDS slot cj <- global slot ci = cj ^ (row&7)
  const int cj0 = tid, cj1 = tid + 256;
  const int ci0 = (cj0 ^ ((cj0 >> 3) & 7)) * 16;
  const int ci1 = (cj1 ^ ((cj1 >> 3) & 7)) * 16;
  const int d0 = cj0 >> 3, d1 = cj1 >> 3;
  const int ch0 = ((cj0 & 7) ^ (d0 & 7)) * 16;
  const int ch1 = ((cj1 & 7) ^ (d1 & 7)) * 16;

  const int kv0 = z * (SLEN / nsplit);
  const char* kp0 = (const char*)Kp + (size_t)(b * SLEN + kv0) * 128 + ci0;
  const char* kp1 = (const char*)Kp + (size_t)(b * SLEN + kv0) * 128 + ci1;
  const char* vp0 =
      (const char*)VpT + ((size_t)(b * HP + d0) * SLEN + kv0) * 2 + ch0;
  const char* vp1 =
      (const char*)VpT + ((size_t)(b * HP + d1) * SLEN + kv0) * 2 + ch1;

  // prologue: load tile 0 and stage into buffer 0 (no barrier needed yet;
  // the loop-top barrier covers visibility)
  {
    f4 k0 = *(const f4*)kp0;
    f4 k1 = *(const f4*)kp1;
    f4 v0 = *(const f4*)vp0;
    f4 v1 = *(const f4*)vp1;
    *(f4*)(Klds[0] + tid * 16) = k0;
    *(f4*)(Klds[0] + tid * 16 + 4096) = k1;
    *(f4*)(Vlds[0] + tid * 16) = v0;
    *(f4*)(Vlds[0] + tid * 16 + 4096) = v1;
    kp0 += KVB * 128;
    kp1 += KVB * 128;
    vp0 += KVB * 2;
    vp1 += KVB * 2;
  }

  f4 oA[4] = {}, oB[4] = {};
  float mA = -1e30f, lsumA = 0.f;
  float mB = -1e30f, lsumB = 0.f;
  const int nsteps = SLEN / nsplit / KVB;
  for (int step = 0; step < nsteps; ++step) {
    const int p = step & 1;
    f4 rk0, rk1, rv0, rv1;
    const bool more = (step + 1 < nsteps);
    if (more) {  // issue next-tile loads; consumed after compute
      rk0 = *(const f4*)kp0;
      rk1 = *(const f4*)kp1;
      rv0 = *(const f4*)vp0;
      rv1 = *(const f4*)vp1;
      kp0 += KVB * 128;
      kp1 += KVB * 128;
      vp0 += KVB * 2;
      vp1 += KVB * 2;
    }
    __syncthreads();  // buf[p] staged (prev iter / prologue) -> visible
    const char* Kbuf = Klds[p];
    const char* Vbuf = Vlds[p];
#pragma unroll
    for (int tt = 0; tt < 4; ++tt) {
      // S^T tile [16 keys x 16 q] = K_tile . Q^T  (C: col=q=l15, row=key=4g+r)
      f4 stA = {}, stB = {};
      {
        s4 kf0 = *(const s4*)(Kbuf + kr0 + tt * 2048);
        s4 kf1 = *(const s4*)(Kbuf + kr1 + tt * 2048);
        s4 kf2 = *(const s4*)(Kbuf + kr2 + tt * 2048);
        s4 kf3 = *(const s4*)(Kbuf + kr3 + tt * 2048);
        __builtin_amdgcn_s_setprio(1);
        stA = __builtin_amdgcn_mfma_f32_16x16x16bf16_1k(kf0, qfA[0], stA, 0, 0, 0);
        stB = __builtin_amdgcn_mfma_f32_16x16x16bf16_1k(kf0, qfB[0], stB, 0, 0, 0);
        stA = __builtin_amdgcn_mfma_f32_16x16x16bf16_1k(kf1, qfA[1], stA, 0, 0, 0);
        stB = __builtin_amdgcn_mfma_f32_16x16x16bf16_1k(kf1, qfB[1], stB, 0, 0, 0);
        stA = __builtin_amdgcn_mfma_f32_16x16x16bf16_1k(kf2, qfA[2], stA, 0, 0, 0);
        stB = __builtin_amdgcn_mfma_f32_16x16x16bf16_1k(kf2, qfB[2], stB, 0, 0, 0);
        stA = __builtin_amdgcn_mfma_f32_16x16x16bf16_1k(kf3, qfA[3], stA, 0, 0, 0);
        stB = __builtin_amdgcn_mfma_f32_16x16x16bf16_1k(kf3, qfB[3], stB, 0, 0, 0);
        __builtin_amdgcn_s_setprio(0);
      }
      // ---- softmax A ----
      float tmaxA = fmaxf(fmaxf(stA[0], stA[1]), fmaxf(stA[2], stA[3]));
      if (__builtin_expect(__any(tmaxA > mA + 8.0f), 0)) {
        float t = fmaxf(tmaxA, __shfl_xor(tmaxA, 16));
        t = fmaxf(t, __shfl_xor(t, 32));
        t = fmaxf(t, mA);
        float corr = fexp2(mA - t);
        lsumA *= corr;
#pragma unroll
        for (int n = 0; n < 4; ++n) {
          oA[n][0] *= corr; oA[n][1] *= corr; oA[n][2] *= corr; oA[n][3] *= corr;
        }
        mA = t;
      }
      float pa0 = fexp2(stA[0] - mA), pa1 = fexp2(stA[1] - mA);
      float pa2 = fexp2(stA[2] - mA), pa3 = fexp2(stA[3] - mA);
      lsumA += (pa0 + pa1) + (pa2 + pa3);
      union { unsigned u[2]; s4 s; } puA;
      asm("v_cvt_pk_bf16_f32 %0, %1, %2" : "=v"(puA.u[0]) : "v"(pa0), "v"(pa1));
      asm("v_cvt_pk_bf16_f32 %0, %1, %2" : "=v"(puA.u[1]) : "v"(pa2), "v"(pa3));
      s4 pfA = puA.s;
      // ---- softmax B ----
      float tmaxB = fmaxf(fmaxf(stB[0], stB[1]), fmaxf(stB[2], stB[3]));
      if (__builtin_expect(__any(tmaxB > mB + 8.0f), 0)) {
        float t = fmaxf(tmaxB, __shfl_xor(tmaxB, 16));
        t = fmaxf(t, __shfl_xor(t, 32));
        t = fmaxf(t, mB);
        float corr = fexp2(mB - t);
        lsumB *= corr;
#pragma unroll
        for (int n = 0; n < 4; ++n) {
          oB[n][0] *= corr; oB[n][1] *= corr; oB[n][2] *= corr; oB[n][3] *= corr;
        }
        mB = t;
      }
      float pb0 = fexp2(stB[0] - mB), pb1 = fexp2(stB[1] - mB);
      float pb2 = fexp2(stB[2] - mB), pb3 = fexp2(stB[3] - mB);
      lsumB += (pb0 + pb1) + (pb2 + pb3);
      union { unsigned u[2]; s4 s; } puB;
      asm("v_cvt_pk_bf16_f32 %0, %1, %2" : "=v"(puB.u[0]) : "v"(pb0), "v"(pb1));
      asm("v_cvt_pk_bf16_f32 %0, %1, %2" : "=v"(puB.u[1]) : "v"(pb2), "v"(pb3));
      s4 pfB = puB.s;
      // O^T[d][q] += V^T . P  (P already in B-frag layout: col=q=l15, k=4g+r)
      const char* vrow = Vbuf + (vb ^ (tt << 5));
      __builtin_amdgcn_s_setprio(1);
#pragma unroll
      for (int n = 0; n < 4; ++n) {
        s4 vf = *(const s4*)(vrow + n * 2048);
        oA[n] = __builtin_amdgcn_mfma_f32_16x16x16bf16_1k(vf, pfA, oA[n], 0, 0, 0);
        oB[n] = __builtin_amdgcn_mfma_f32_16x16x16bf16_1k(vf, pfB, oB[n], 0, 0, 0);
      }
      __builtin_amdgcn_s_setprio(0);
    }
    if (more) {  // stage next tile into the other buffer (no barrier here;
                 // next iteration's top barrier orders it before its readers)
      *(f4*)(Klds[p ^ 1] + tid * 16) = rk0;
      *(f4*)(Klds[p ^ 1] + tid * 16 + 4096) = rk1;
      *(f4*)(Vlds[p ^ 1] + tid * 16) = rv0;
      *(f4*)(Vlds[p ^ 1] + tid * 16 + 4096) = rv1;
    }
  }
  lsumA += __shfl_xor(lsumA, 16);
  lsumA += __shfl_xor(lsumA, 32);
  lsumB += __shfl_xor(lsumB, 16);
  lsumB += __shfl_xor(lsumB, 32);
  const int rowgA = b * SLEN + qrowA;
  const int rowgB = b * SLEN + qrowB;
  const int NR = NB * SLEN;
  if (lane < 16) {
    Mp[z * NR + rowgA] = mA;
    Lp[z * NR + rowgA] = lsumA;
    Mp[z * NR + rowgB] = mB;
    Lp[z * NR + rowgB] = lsumB;
  }
  float* opA = Op + ((size_t)z * NR + rowgA) * HP;
  float* opB = Op + ((size_t)z * NR + rowgB) * HP;
#pragma unroll
  for (int n = 0; n < 4; ++n) {
    *(f4*)(opA + 16 * n + 4 * g) = oA[n];
    *(f4*)(opB + 16 * n + 4 * g) = oB[n];
  }
}

// ------- fused: merge KV-split partials + normalize + out-projection ---------
template <int NSPLIT>
__global__ __launch_bounds__(256) void combineproj_kernel(
    const float* __restrict__ Mp, const float* __restrict__ Lp,
    const float* __restrict__ Op, const short* __restrict__ wot,
    float* __restrict__ out) {
  const int lane = threadIdx.x & 63, wid = threadIdx.x >> 6;
  const int l15 = lane & 15, g = lane >> 4;
  const int sbase = blockIdx.x * 64 + wid * 16;
  const int row = sbase + l15;
  const int NR = NB * SLEN;
  float mm = -1e30f;
#pragma unroll
  for (int s = 0; s < NSPLIT; ++s) mm = fmaxf(mm, Mp[s * NR + row]);
  float w[NSPLIT];
  float L = 0.f;
#pragma unroll
  for (int s = 0; s < NSPLIT; ++s) {
    w[s] = fexp2(Mp[s * NR + row] - mm);
    L += w[s] * Lp[s * NR + row];
  }
  float inv = 1.0f / L;
  s4 af[4];
#pragma unroll
  for (int c = 0; c < 4; ++c) {
    f4 acc = {};
#pragma unroll
    for (int s = 0; s < NSPLIT; ++s) {
      f4 vv = *(const f4*)(Op + ((size_t)s * NR + row) * HP + 16 * c + 4 * g);
      acc[0] += w[s] * vv[0];
      acc[1] += w[s] * vv[1];
      acc[2] += w[s] * vv[2];
      acc[3] += w[s] * vv[3];
    }
#pragma unroll
    for (int r = 0; r < 4; ++r) af[c][r] = f2bf(acc[r] * inv);
  }
  for (int n = 0; n < 13; ++n) {
    f4 acc = {};
    const short* brow = wot + (16 * n + l15) * HP + 4 * g;
#pragma unroll
    for (int c = 0; c < 4; ++c) {
      s4 bf = *(const s4*)(brow + 16 * c);
      acc = __builtin_amdgcn_mfma_f32_16x16x16bf16_1k(af[c], bf, acc, 0, 0, 0);
    }
    int dm = 16 * n + l15;
    if (dm < DMODEL) {
#pragma unroll
      for (int r = 0; r < 4; ++r) {
        int rr = sbase + 4 * g + r;
        out[(size_t)rr * DMODEL + dm] = acc[r];
      }
    }
  }
}

extern "C" void kernel_launch(void* const* d_in, const int* in_sizes, int n_in,
                              void* d_out, int out_size, void* d_ws, size_t ws_size,
                              hipStream_t stream) {
  const float* q = (const float*)d_in[0];
  const float* k = (const float*)d_in[1];
  const float* v = (const float*)d_in[2];
  const float* WQ = (const float*)d_in[3];
  const float* WK = (const float*)d_in[4];
  const float* WV = (const float*)d_in[5];
  const float* WO = (const float*)d_in[6];
  float* out = (float*)d_out;
  char* ws = (char*)d_ws;

  const size_t MB2 = 2097152;  // 16384*64*2 bytes
  const size_t NR = (size_t)NB * SLEN;
  // choose KV-split by available workspace
  size_t need8 = 131072 + 4 * MB2 + 8 * NR * 4 * 2 + 8 * NR * HP * 4;
  int nsplit = (ws_size >= need8) ? 8 : 4;

  short* wqt = (short*)(ws + 0);
  short* wkt = (short*)(ws + 32768);
  short* wvt = (short*)(ws + 65536);
  short* wot = (short*)(ws + 98304);
  short* Qp = (short*)(ws + 131072);
  short* Kp = (short*)(ws + 131072 + MB2);
  short* VpT = (short*)(ws + 131072 + 2 * MB2);
  float* Mp = (float*)(ws + 131072 + 4 * MB2);
  float* Lp = Mp + nsplit * NR;
  float* Op = Lp + nsplit * NR;

  prep_weights<<<dim3(208), dim3(256), 0, stream>>>(WQ, WK, WV, WO, wqt, wkt, wvt, wot);
  proj_kernel<<<dim3(256, 1, 3), dim3(256), 0, stream>>>(q, k, v, wqt, wkt, wvt, Qp, Kp, VpT);
  attn_kernel<<<dim3(32, NB, nsplit), dim3(256), 0, stream>>>(Qp, Kp, VpT, Mp, Lp, Op);
  if (nsplit == 8)
    combineproj_kernel<8><<<dim3(256), dim3(256), 0, stream>>>(Mp, Lp, Op, wot, out);
  else
    combineproj_kernel<4><<<dim3(256), dim3(256), 0, stream>>>(Mp, Lp, Op, wot, out);
}

// Round 9
// 69.943 us; speedup vs baseline: 1.4194x; 1.0324x over previous
//
#include <hip/hip_runtime.h>
#include <hip/hip_bf16.h>

// Problem: B=4, S=4096, D_MODEL=200, head=50 (padded to 64), out fp32.
// Pipeline: prep_weights -> proj (MFMA) -> flash attn (MFMA, KV-split,
//           ping-pong LDS single-barrier pipeline, 2 q-tiles/wave, K=32
//           QK^T MFMA, T5 setprio) -> fused combine+outproj (MFMA).

typedef short s4 __attribute__((ext_vector_type(4)));
typedef short s8 __attribute__((ext_vector_type(8)));
typedef float f4 __attribute__((ext_vector_type(4)));

#define SLEN 4096
#define NB 4
#define DMODEL 200
#define HREAL 50
#define HP 64
#define DMP 208
#define KVB 64
// (1/sqrt(50)) * log2(e) folded into WQ so softmax uses exp2 (v_exp_f32)
#define QSCALE 0.20402789f

__device__ __forceinline__ short f2bf(float f) {
  unsigned u = __builtin_bit_cast(unsigned, f);
  u += 0x7FFFu + ((u >> 16) & 1u);
  return (short)(u >> 16);
}

__device__ __forceinline__ float fexp2(float x) { return __builtin_amdgcn_exp2f(x); }

// ---------------- weight prep: transpose+pad+bf16 (and sum WO head blocks) ---
__global__ void prep_weights(const float* __restrict__ WQ, const float* __restrict__ WK,
                             const float* __restrict__ WV, const float* __restrict__ WO,
                             short* __restrict__ wqt, short* __restrict__ wkt,
                             short* __restrict__ wvt, short* __restrict__ wot) {
  int id = blockIdx.x * 256 + threadIdx.x;
  const int NW = HP * DMP;  // 13312
  if (id < 3 * NW) {
    int which = id / NW, rem = id % NW;
    int e = rem / DMP, d = rem % DMP;
    float v = 0.f;
    if (e < HREAL && d < DMODEL) {
      const float* W = (which == 0) ? WQ : (which == 1 ? WK : WV);
      v = W[d * HREAL + e];
      if (which == 0) v *= QSCALE;
    }
    short* T = (which == 0) ? wqt : (which == 1 ? wkt : wvt);
    T[e * DMP + d] = f2bf(v);
  } else if (id < 4 * NW) {
    int rem = id - 3 * NW;
    int dm = rem / HP, e = rem % HP;
    float v = 0.f;
    if (dm < DMODEL && e < HREAL) {
      v = WO[(e)*DMODEL + dm] + WO[(HREAL + e) * DMODEL + dm] +
          WO[(2 * HREAL + e) * DMODEL + dm] + WO[(3 * HREAL + e) * DMODEL + dm];
    }
    wot[dm * HP + e] = f2bf(v);
  }
}

// ---------------- projections: X[16384,200] @ WT^T -> bf16 [16384,64] --------
// mode 0: q->Qp (scaled), 1: k->Kp, 2: v->VpT (transposed store [B][64][S])
__global__ __launch_bounds__(256) void proj_kernel(
    const float* __restrict__ q, const float* __restrict__ k, const float* __restrict__ v,
    const short* __restrict__ wqt, const short* __restrict__ wkt, const short* __restrict__ wvt,
    short* __restrict__ Qp, short* __restrict__ Kp, short* __restrict__ VpT) {
  const int mode = blockIdx.z;
  const float* X = (mode == 0) ? q : (mode == 1 ? k : v);
  const short* WT = (mode == 0) ? wqt : (mode == 1 ? wkt : wvt);
  const int lane = threadIdx.x & 63, wid = threadIdx.x >> 6;
  const int l15 = lane & 15, g = lane >> 4;
  const int sbase = blockIdx.x * 64 + wid * 16;
  const int row = sbase + l15;
  f4 acc[4] = {};
  for (int c = 0; c < 13; ++c) {
    int d0 = 16 * c + 4 * g;
    f4 a4 = {};
    if (d0 < DMODEL) a4 = *(const f4*)(X + (size_t)row * DMODEL + d0);
    s4 af;
#pragma unroll
    for (int j = 0; j < 4; ++j) af[j] = f2bf(a4[j]);
#pragma unroll
    for (int n = 0; n < 4; ++n) {
      s4 bf = *(const s4*)(WT + (16 * n + l15) * DMP + d0);
      acc[n] = __builtin_amdgcn_mfma_f32_16x16x16bf16_1k(af, bf, acc[n], 0, 0, 0);
    }
  }
  if (mode < 2) {
    short* OUT = (mode == 0) ? Qp : Kp;
#pragma unroll
    for (int n = 0; n < 4; ++n)
#pragma unroll
      for (int r = 0; r < 4; ++r) {
        int rr = sbase + 4 * g + r;
        OUT[rr * HP + 16 * n + l15] = f2bf(acc[n][r]);
      }
  } else {
#pragma unroll
    for (int n = 0; n < 4; ++n)
#pragma unroll
      for (int r = 0; r < 4; ++r) {
        int rr = sbase + 4 * g + r;
        int bb = rr >> 12, s = rr & 4095;
        VpT[((bb * HP) + 16 * n + l15) * SLEN + s] = f2bf(acc[n][r]);
      }
  }
}

// ---------------- flash attention, swapped-operand QK^T, KV-split ------------
// LDS content: linear dest, inverse-swizzled global source (involution xor of
// byte bits 4-6 with row&7). Reads apply the same xor -> conflict-free.
// Ping-pong double buffer, single barrier/step. QK^T uses the native gfx950
// K=32 MFMA (s8 fragments); PV keeps the verified _1k path.
__global__ __launch_bounds__(256, 4) void attn_kernel(
    const short* __restrict__ Qp, const short* __restrict__ Kp,
    const short* __restrict__ VpT, float* __restrict__ Mp,
    float* __restrict__ Lp, float* __restrict__ Op) {
  __shared__ __align__(16) char Klds[2][KVB * 128];  // 2 x 8KB, swizzled
  __shared__ __align__(16) char Vlds[2][HP * 128];   // 2 x 8KB, swizzled
  const int tid = threadIdx.x;
  const int lane = tid & 63, wid = tid >> 6;
  const int l15 = lane & 15, g = lane >> 4;
  const int b = blockIdx.y, z = blockIdx.z;
  const int nsplit = gridDim.z;
  const int qrowA = blockIdx.x * 128 + wid * 32 + l15;
  const int qrowB = qrowA + 16;
  const int ksw = (l15 & 7) << 4;

  // Q fragments for K=32 MFMA: lane group g holds d 8g..8g+7 (+32 for frag 1)
  s8 qfA[2], qfB[2];
  {
    const short* qpa = Qp + (size_t)(b * SLEN + qrowA) * HP + 8 * g;
    const short* qpb = Qp + (size_t)(b * SLEN + qrowB) * HP + 8 * g;
    qfA[0] = *(const s8*)(qpa);
    qfA[1] = *(const s8*)(qpa + 32);
    qfB[0] = *(const s8*)(qpb);
    qfB[1] = *(const s8*)(qpb + 32);
  }

  // LDS read base offsets (bytes), loop-invariant; inner addr = base + tt*2048
  const int kr0 = l15 * 128 + ((16 * g) ^ ksw);
  const int kr1 = l15 * 128 + ((64 + 16 * g) ^ ksw);
  const int vb = l15 * 128 + ((8 * g) ^ ksw);

  // staging: linear LDS slot cj <- global slot ci = cj ^ (row&7)
  const int cj0 = tid, cj1 = tid + 256;
  const int ci0 = (cj0 ^ ((cj0 >> 3) & 7)) * 16;
  const int ci1 = (cj1 ^ ((cj1 >> 3) & 7)) * 16;
  const int d0 = cj0 >> 3, d1 = cj1 >> 3;
  const int ch0 = ((cj0 & 7) ^ (d0 & 7)) * 16;
  const int ch1 = ((cj1 & 7) ^ (d1 & 7)) * 16;

  const int kv0 = z * (SLEN / nsplit);
  const char* kp0 = (const char*)Kp + (size_t)(b * SLEN + kv0) * 128 + ci0;
  const char* kp1 = (const char*)Kp + (size_t)(b * SLEN + kv0) * 128 + ci1;
  const char* vp0 =
      (const char*)VpT + ((size_t)(b * HP + d0) * SLEN + kv0) * 2 + ch0;
  const char* vp1 =
      (const char*)VpT + ((size_t)(b * HP + d1) * SLEN + kv0) * 2 + ch1;

  // prologue: load tile 0 and stage into buffer 0
  {
    f4 k0 = *(const f4*)kp0;
    f4 k1 = *(const f4*)kp1;
    f4 v0 = *(const f4*)vp0;
    f4 v1 = *(const f4*)vp1;
    *(f4*)(Klds[0] + tid * 16) = k0;
    *(f4*)(Klds[0] + tid * 16 + 4096) = k1;
    *(f4*)(Vlds[0] + tid * 16) = v0;
    *(f4*)(Vlds[0] + tid * 16 + 4096) = v1;
    kp0 += KVB * 128;
    kp1 += KVB * 128;
    vp0 += KVB * 2;
    vp1 += KVB * 2;
  }

  f4 oA[4] = {}, oB[4] = {};
  float mA = -1e30f, lsumA = 0.f;
  float mB = -1e30f, lsumB = 0.f;
  const int nsteps = SLEN / nsplit / KVB;
  for (int step = 0; step < nsteps; ++step) {
    const int p = step & 1;
    f4 rk0, rk1, rv0, rv1;
    const bool more = (step + 1 < nsteps);
    if (more) {  // issue next-tile loads; consumed after compute
      rk0 = *(const f4*)kp0;
      rk1 = *(const f4*)kp1;
      rv0 = *(const f4*)vp0;
      rv1 = *(const f4*)vp1;
      kp0 += KVB * 128;
      kp1 += KVB * 128;
      vp0 += KVB * 2;
      vp1 += KVB * 2;
    }
    __syncthreads();  // buf[p] staged (prev iter / prologue) -> visible
    const char* Kbuf = Klds[p];
    const char* Vbuf = Vlds[p];
#pragma unroll
    for (int tt = 0; tt < 4; ++tt) {
      // S^T tile [16 keys x 16 q] = K_tile . Q^T  (C: col=q=l15, row=key=4g+r)
      f4 stA = {}, stB = {};
      {
        s8 kf0 = *(const s8*)(Kbuf + kr0 + tt * 2048);
        s8 kf1 = *(const s8*)(Kbuf + kr1 + tt * 2048);
        __builtin_amdgcn_s_setprio(1);
        stA = __builtin_amdgcn_mfma_f32_16x16x32_bf16(kf0, qfA[0], stA, 0, 0, 0);
        stB = __builtin_amdgcn_mfma_f32_16x16x32_bf16(kf0, qfB[0], stB, 0, 0, 0);
        stA = __builtin_amdgcn_mfma_f32_16x16x32_bf16(kf1, qfA[1], stA, 0, 0, 0);
        stB = __builtin_amdgcn_mfma_f32_16x16x32_bf16(kf1, qfB[1], stB, 0, 0, 0);
        __builtin_amdgcn_s_setprio(0);
      }
      // ---- softmax A ----
      float tmaxA = fmaxf(fmaxf(stA[0], stA[1]), fmaxf(stA[2], stA[3]));
      if (__builtin_expect(__any(tmaxA > mA + 8.0f), 0)) {
        float t = fmaxf(tmaxA, __shfl_xor(tmaxA, 16));
        t = fmaxf(t, __shfl_xor(t, 32));
        t = fmaxf(t, mA);
        float corr = fexp2(mA - t);
        lsumA *= corr;
#pragma unroll
        for (int n = 0; n < 4; ++n) {
          oA[n][0] *= corr; oA[n][1] *= corr; oA[n][2] *= corr; oA[n][3] *= corr;
        }
        mA = t;
      }
      float pa0 = fexp2(stA[0] - mA), pa1 = fexp2(stA[1] - mA);
      float pa2 = fexp2(stA[2] - mA), pa3 = fexp2(stA[3] - mA);
      lsumA += (pa0 + pa1) + (pa2 + pa3);
      union { unsigned u[2]; s4 s; } puA;
      asm("v_cvt_pk_bf16_f32 %0, %1, %2" : "=v"(puA.u[0]) : "v"(pa0), "v"(pa1));
      asm("v_cvt_pk_bf16_f32 %0, %1, %2" : "=v"(puA.u[1]) : "v"(pa2), "v"(pa3));
      s4 pfA = puA.s;
      // ---- softmax B ----
      float tmaxB = fmaxf(fmaxf(stB[0], stB[1]), fmaxf(stB[2], stB[3]));
      if (__builtin_expect(__any(tmaxB > mB + 8.0f), 0)) {
        float t = fmaxf(tmaxB, __shfl_xor(tmaxB, 16));
        t = fmaxf(t, __shfl_xor(t, 32));
        t = fmaxf(t, mB);
        float corr = fexp2(mB - t);
        lsumB *= corr;
#pragma unroll
        for (int n = 0; n < 4; ++n) {
          oB[n][0] *= corr; oB[n][1] *= corr; oB[n][2] *= corr; oB[n][3] *= corr;
        }
        mB = t;
      }
      float pb0 = fexp2(stB[0] - mB), pb1 = fexp2(stB[1] - mB);
      float pb2 = fexp2(stB[2] - mB), pb3 = fexp2(stB[3] - mB);
      lsumB += (pb0 + pb1) + (pb2 + pb3);
      union { unsigned u[2]; s4 s; } puB;
      asm("v_cvt_pk_bf16_f32 %0, %1, %2" : "=v"(puB.u[0]) : "v"(pb0), "v"(pb1));
      asm("v_cvt_pk_bf16_f32 %0, %1, %2" : "=v"(puB.u[1]) : "v"(pb2), "v"(pb3));
      s4 pfB = puB.s;
      // O^T[d][q] += V^T . P  (P already in B-frag layout: col=q=l15, k=4g+r)
      const char* vrow = Vbuf + (vb ^ (tt << 5));
      __builtin_amdgcn_s_setprio(1);
#pragma unroll
      for (int n = 0; n < 4; ++n) {
        s4 vf = *(const s4*)(vrow + n * 2048);
        oA[n] = __builtin_amdgcn_mfma_f32_16x16x16bf16_1k(vf, pfA, oA[n], 0, 0, 0);
        oB[n] = __builtin_amdgcn_mfma_f32_16x16x16bf16_1k(vf, pfB, oB[n], 0, 0, 0);
      }
      __builtin_amdgcn_s_setprio(0);
    }
    if (more) {  // stage next tile into the other buffer
      *(f4*)(Klds[p ^ 1] + tid * 16) = rk0;
      *(f4*)(Klds[p ^ 1] + tid * 16 + 4096) = rk1;
      *(f4*)(Vlds[p ^ 1] + tid * 16) = rv0;
      *(f4*)(Vlds[p ^ 1] + tid * 16 + 4096) = rv1;
    }
  }
  lsumA += __shfl_xor(lsumA, 16);
  lsumA += __shfl_xor(lsumA, 32);
  lsumB += __shfl_xor(lsumB, 16);
  lsumB += __shfl_xor(lsumB, 32);
  const int rowgA = b * SLEN + qrowA;
  const int rowgB = b * SLEN + qrowB;
  const int NR = NB * SLEN;
  if (lane < 16) {
    Mp[z * NR + rowgA] = mA;
    Lp[z * NR + rowgA] = lsumA;
    Mp[z * NR + rowgB] = mB;
    Lp[z * NR + rowgB] = lsumB;
  }
  float* opA = Op + ((size_t)z * NR + rowgA) * HP;
  float* opB = Op + ((size_t)z * NR + rowgB) * HP;
#pragma unroll
  for (int n = 0; n < 4; ++n) {
    *(f4*)(opA + 16 * n + 4 * g) = oA[n];
    *(f4*)(opB + 16 * n + 4 * g) = oB[n];
  }
}

// ------- fused: merge KV-split partials + normalize + out-projection ---------
template <int NSPLIT>
__global__ __launch_bounds__(256) void combineproj_kernel(
    const float* __restrict__ Mp, const float* __restrict__ Lp,
    const float* __restrict__ Op, const short* __restrict__ wot,
    float* __restrict__ out) {
  const int lane = threadIdx.x & 63, wid = threadIdx.x >> 6;
  const int l15 = lane & 15, g = lane >> 4;
  const int sbase = blockIdx.x * 64 + wid * 16;
  const int row = sbase + l15;
  const int NR = NB * SLEN;
  float mm = -1e30f;
#pragma unroll
  for (int s = 0; s < NSPLIT; ++s) mm = fmaxf(mm, Mp[s * NR + row]);
  float w[NSPLIT];
  float L = 0.f;
#pragma unroll
  for (int s = 0; s < NSPLIT; ++s) {
    w[s] = fexp2(Mp[s * NR + row] - mm);
    L += w[s] * Lp[s * NR + row];
  }
  float inv = 1.0f / L;
  s4 af[4];
#pragma unroll
  for (int c = 0; c < 4; ++c) {
    f4 acc = {};
#pragma unroll
    for (int s = 0; s < NSPLIT; ++s) {
      f4 vv = *(const f4*)(Op + ((size_t)s * NR + row) * HP + 16 * c + 4 * g);
      acc[0] += w[s] * vv[0];
      acc[1] += w[s] * vv[1];
      acc[2] += w[s] * vv[2];
      acc[3] += w[s] * vv[3];
    }
#pragma unroll
    for (int r = 0; r < 4; ++r) af[c][r] = f2bf(acc[r] * inv);
  }
  for (int n = 0; n < 13; ++n) {
    f4 acc = {};
    const short* brow = wot + (16 * n + l15) * HP + 4 * g;
#pragma unroll
    for (int c = 0; c < 4; ++c) {
      s4 bf = *(const s4*)(brow + 16 * c);
      acc = __builtin_amdgcn_mfma_f32_16x16x16bf16_1k(af[c], bf, acc, 0, 0, 0);
    }
    int dm = 16 * n + l15;
    if (dm < DMODEL) {
#pragma unroll
      for (int r = 0; r < 4; ++r) {
        int rr = sbase + 4 * g + r;
        out[(size_t)rr * DMODEL + dm] = acc[r];
      }
    }
  }
}

extern "C" void kernel_launch(void* const* d_in, const int* in_sizes, int n_in,
                              void* d_out, int out_size, void* d_ws, size_t ws_size,
                              hipStream_t stream) {
  const float* q = (const float*)d_in[0];
  const float* k = (const float*)d_in[1];
  const float* v = (const float*)d_in[2];
  const float* WQ = (const float*)d_in[3];
  const float* WK = (const float*)d_in[4];
  const float* WV = (const float*)d_in[5];
  const float* WO = (const float*)d_in[6];
  float* out = (float*)d_out;
  char* ws = (char*)d_ws;

  const size_t MB2 = 2097152;  // 16384*64*2 bytes
  const size_t NR = (size_t)NB * SLEN;
  // choose KV-split by available workspace
  size_t need8 = 131072 + 4 * MB2 + 8 * NR * 4 * 2 + 8 * NR * HP * 4;
  int nsplit = (ws_size >= need8) ? 8 : 4;

  short* wqt = (short*)(ws + 0);
  short* wkt = (short*)(ws + 32768);
  short* wvt = (short*)(ws + 65536);
  short* wot = (short*)(ws + 98304);
  short* Qp = (short*)(ws + 131072);
  short* Kp = (short*)(ws + 131072 + MB2);
  short* VpT = (short*)(ws + 131072 + 2 * MB2);
  float* Mp = (float*)(ws + 131072 + 4 * MB2);
  float* Lp = Mp + nsplit * NR;
  float* Op = Lp + nsplit * NR;

  prep_weights<<<dim3(208), dim3(256), 0, stream>>>(WQ, WK, WV, WO, wqt, wkt, wvt, wot);
  proj_kernel<<<dim3(256, 1, 3), dim3(256), 0, stream>>>(q, k, v, wqt, wkt, wvt, Qp, Kp, VpT);
  attn_kernel<<<dim3(32, NB, nsplit), dim3(256), 0, stream>>>(Qp, Kp, VpT, Mp, Lp, Op);
  if (nsplit == 8)
    combineproj_kernel<8><<<dim3(256), dim3(256), 0, stream>>>(Mp, Lp, Op, wot, out);
  else
    combineproj_kernel<4><<<dim3(256), dim3(256), 0, stream>>>(Mp, Lp, Op, wot, out);
}